// Round 1
// baseline (317.496 us; speedup 1.0000x reference)
//
#include <hip/hip_runtime.h>
#include <math.h>

#define NUM 2048
#define CDIM 256
#define NUM_LAYER 4

typedef _Float16 f16x8 __attribute__((ext_vector_type(8)));
typedef unsigned short u16x8 __attribute__((ext_vector_type(8)));
typedef float f32x4 __attribute__((ext_vector_type(4)));

// 2-way fp16 split: x = hi + lo + eps, |eps| <= |x| * 2^-23 (11+11 mantissa bits).
static __device__ __forceinline__ void split_f16(float x, unsigned short& h,
                                                 unsigned short& l) {
  _Float16 hi = (_Float16)x;           // RNE
  float r = x - (float)hi;             // exact (Sterbenz-ish, r tiny)
  _Float16 lo = (_Float16)r;
  h = __builtin_bit_cast(unsigned short, hi);
  l = __builtin_bit_cast(unsigned short, lo);
}

// ---------------- projection + fp16 2-way split (x = hi + lo). Epilogue
// transposes through LDS so component stores are coalesced.
__global__ __launch_bounds__(256) void proj_kernel(
    const float* __restrict__ Wq, const float* __restrict__ bq,
    const float* __restrict__ Wk, const float* __restrict__ bk,
    const float* __restrict__ vf, const float* __restrict__ ef,
    unsigned short* __restrict__ Qhi, unsigned short* __restrict__ Qlo,
    unsigned short* __restrict__ Khi, unsigned short* __restrict__ Klo)
{
  const int z = blockIdx.z;
  const int b = z >> 1, mm2 = z & 1;
  const float* __restrict__ Wmat = mm2 ? Wk : Wq;
  const float* __restrict__ bias = mm2 ? bk : bq;
  const float* __restrict__ x = (mm2 ? ef : vf) + (size_t)b * CDIM * NUM;
  unsigned short* __restrict__ ohi = mm2 ? Khi : Qhi;
  unsigned short* __restrict__ olo = mm2 ? Klo : Qlo;

  const int n0 = blockIdx.x * 64;
  const int o0 = blockIdx.y * 64;
  __shared__ float Xs[32][65];
  __shared__ float Ws[64][33];
  __shared__ float T[64][69];
  const int t = threadIdx.x;
  const int tx = t & 15, ty = t >> 4;

  float acc[4][4];
  #pragma unroll
  for (int a = 0; a < 4; a++)
    #pragma unroll
    for (int c = 0; c < 4; c++) acc[a][c] = 0.0f;

  for (int cc = 0; cc < CDIM; cc += 32) {
    #pragma unroll
    for (int e = 0; e < 2; e++) {
      int f = t * 2 + e;
      int row = f >> 4, c4 = f & 15;
      const float4 v = *(const float4*)(&x[(size_t)(cc + row) * NUM + n0 + c4 * 4]);
      Xs[row][c4*4+0] = v.x; Xs[row][c4*4+1] = v.y;
      Xs[row][c4*4+2] = v.z; Xs[row][c4*4+3] = v.w;
    }
    #pragma unroll
    for (int e = 0; e < 2; e++) {
      int f = t * 2 + e;
      int row = f >> 3, c4 = f & 7;
      const float4 v = *(const float4*)(&Wmat[(size_t)(o0 + row) * CDIM + cc + c4 * 4]);
      Ws[row][c4*4+0] = v.x; Ws[row][c4*4+1] = v.y;
      Ws[row][c4*4+2] = v.z; Ws[row][c4*4+3] = v.w;
    }
    __syncthreads();
    #pragma unroll
    for (int kk = 0; kk < 32; kk++) {
      float xv[4], wv[4];
      #pragma unroll
      for (int j = 0; j < 4; j++) xv[j] = Xs[kk][tx*4+j];
      #pragma unroll
      for (int j = 0; j < 4; j++) wv[j] = Ws[ty*4+j][kk];
      #pragma unroll
      for (int oi = 0; oi < 4; oi++)
        #pragma unroll
        for (int ni = 0; ni < 4; ni++)
          acc[oi][ni] = fmaf(wv[oi], xv[ni], acc[oi][ni]);
    }
    __syncthreads();
  }
  float bb[4];
  #pragma unroll
  for (int oi = 0; oi < 4; oi++) bb[oi] = bias[o0 + ty*4 + oi];
  #pragma unroll
  for (int ni = 0; ni < 4; ni++)
    #pragma unroll
    for (int oi = 0; oi < 4; oi++)
      T[tx*4+ni][ty*4+oi] = acc[oi][ni] + bb[oi];
  __syncthreads();
  const int n_l = t >> 2;
  const int oc  = (t & 3) * 16;
  float xv[16];
  #pragma unroll
  for (int j = 0; j < 16; j++) xv[j] = T[n_l][oc + j];
  unsigned short hi[16], lo[16];
  #pragma unroll
  for (int j = 0; j < 16; j++) split_f16(xv[j], hi[j], lo[j]);
  const size_t gb = ((size_t)b * NUM + n0 + n_l) * CDIM + o0 + oc;
  *(u16x8*)&ohi[gb]   = *(u16x8*)&hi[0];
  *(u16x8*)&ohi[gb+8] = *(u16x8*)&hi[8];
  *(u16x8*)&olo[gb]   = *(u16x8*)&lo[0];
  *(u16x8*)&olo[gb+8] = *(u16x8*)&lo[8];
}

// ---------------- score via MFMA (fp16 2-way split, 3 products hh+hl+lh:
// 22-bit effective mantissa, omitted ll term is O(2^-22) relative — same
// accuracy class as the previous bf16 3-way/6-product scheme at half the
// MFMA count and 2/3 the LDS traffic).
// 512 threads / 8 waves, 128x128 tile, wave tile 64(o)x32(i), stride-36 LDS,
// reg-prefetch next head. LDS 36.9KB -> target 3 blocks/CU (24 waves).
__global__ __launch_bounds__(512, 6) void score_kernel(
    const unsigned short* __restrict__ Qhi, const unsigned short* __restrict__ Qlo,
    const unsigned short* __restrict__ Khi, const unsigned short* __restrict__ Klo,
    const float* __restrict__ H0, float* __restrict__ score)
{
  const int b = blockIdx.z;
  const int i0 = blockIdx.x * 128;
  const int o0 = blockIdx.y * 128;
  const int t = threadIdx.x, lane = t & 63, wave = t >> 6;
  const int m = lane & 15, quad = lane >> 4;
  const int obl = (wave & 1) * 64;
  const int ibl = (wave >> 1) * 32;

  __shared__ unsigned short qsh[2][128][36];
  __shared__ unsigned short ksh[2][128][36];

  const int srow = t >> 2;
  const int schk = (t & 3) * 8;

  f32x4 ssum[4][2];
  #pragma unroll
  for (int a = 0; a < 4; a++)
    #pragma unroll
    for (int c = 0; c < 2; c++) ssum[a][c] = (f32x4){0.f, 0.f, 0.f, 0.f};

  const float SC = -1.4426950408889634f * 0.17677669529663687f;  // -log2(e)/sqrt(32)

  u16x8 pq[2], pk[2];
  {
    const size_t go = ((size_t)b * NUM + o0 + srow) * CDIM + schk;
    const size_t gi = ((size_t)b * NUM + i0 + srow) * CDIM + schk;
    pq[0] = *(const u16x8*)&Qhi[go];
    pq[1] = *(const u16x8*)&Qlo[go];
    pk[0] = *(const u16x8*)&Khi[gi];
    pk[1] = *(const u16x8*)&Klo[gi];
  }

  for (int h = 0; h < 8; h++) {
    __syncthreads();
    #pragma unroll
    for (int cp = 0; cp < 2; cp++) {
      *(u16x8*)&qsh[cp][srow][schk] = pq[cp];
      *(u16x8*)&ksh[cp][srow][schk] = pk[cp];
    }
    __syncthreads();
    if (h < 7) {
      const int coff = (h + 1) * 32;
      const size_t go = ((size_t)b * NUM + o0 + srow) * CDIM + coff + schk;
      const size_t gi = ((size_t)b * NUM + i0 + srow) * CDIM + coff + schk;
      pq[0] = *(const u16x8*)&Qhi[go];
      pq[1] = *(const u16x8*)&Qlo[go];
      pk[0] = *(const u16x8*)&Khi[gi];
      pk[1] = *(const u16x8*)&Klo[gi];
    }
    f16x8 a[4][2];
    #pragma unroll
    for (int ot = 0; ot < 4; ot++)
      #pragma unroll
      for (int cp = 0; cp < 2; cp++)
        a[ot][cp] = *(const f16x8*)&qsh[cp][obl + ot*16 + m][quad*8];
    #pragma unroll
    for (int it = 0; it < 2; it++) {
      const f16x8 b0 = *(const f16x8*)&ksh[0][ibl + it*16 + m][quad*8];
      const f16x8 b1 = *(const f16x8*)&ksh[1][ibl + it*16 + m][quad*8];
      #pragma unroll
      for (int ot = 0; ot < 4; ot++) {
        f32x4 c = (f32x4){0.f, 0.f, 0.f, 0.f};
        c = __builtin_amdgcn_mfma_f32_16x16x32_f16(a[ot][0], b0, c, 0, 0, 0); // hh
        c = __builtin_amdgcn_mfma_f32_16x16x32_f16(a[ot][0], b1, c, 0, 0, 0); // hl
        c = __builtin_amdgcn_mfma_f32_16x16x32_f16(a[ot][1], b0, c, 0, 0, 0); // lh
        #pragma unroll
        for (int r = 0; r < 4; r++)
          ssum[ot][it][r] += __builtin_amdgcn_rcpf(1.0f + __builtin_amdgcn_exp2f(c[r] * SC));
      }
    }
  }
  const int ob = o0 + obl, ib = i0 + ibl;
  #pragma unroll
  for (int ot = 0; ot < 4; ot++)
    #pragma unroll
    for (int it = 0; it < 2; it++)
      #pragma unroll
      for (int r = 0; r < 4; r++) {
        const int row = ob + ot*16 + quad*4 + r;
        const int col = ib + it*16 + m;
        const size_t idx = ((size_t)b * NUM + row) * NUM + col;
        score[idx] = H0[idx] * ssum[ot][it][r] * 0.125f;
      }
}

// ---------------- barrier-free fused topk+apply: ONE WAVE PER ROW.
// Each wave: private 1KB LDS histogram, 4-pass radix select (zero, count,
// 64-lane suffix scan, ballot+shfl select — all wave-internal, no s_barrier),
// then W/H/Dv write. Same select invariant as the verified block version.
__global__ __launch_bounds__(256) void topk_apply_kernel(
    float* __restrict__ scoreW, float* __restrict__ Hout,
    const int* __restrict__ iterp, float* __restrict__ DvOut)
{
  const int wave = threadIdx.x >> 6, lane = threadIdx.x & 63;
  const int row = blockIdx.x * 4 + wave;
  __shared__ unsigned int hist_all[4][256];
  unsigned int* __restrict__ h = hist_all[wave];
  unsigned int* __restrict__ srow = (unsigned int*)scoreW + (size_t)row * NUM;
  float* __restrict__ Hrow = Hout + (size_t)row * NUM;

  uint4 v[8];
  #pragma unroll
  for (int q = 0; q < 8; q++) v[q] = ((const uint4*)srow)[lane + 64*q];

  const int it = iterp[0];
  int k = (int)((double)NUM * 0.1 * (double)(NUM_LAYER - 1 - it) + 0.5);
  if (k < 1) k = 1;
  if (k > NUM) k = NUM;

  unsigned int prefix = 0;
  unsigned int rem = (unsigned int)k;

  for (int pass = 3; pass >= 0; pass--) {
    const int shift = pass * 8;
    const unsigned int pmask = (pass == 3) ? 0u : (0xFFFFFFFFu << (shift + 8));
    *(uint4*)&h[lane*4] = make_uint4(0u, 0u, 0u, 0u);
    __threadfence_block();
    unsigned int zc = 0;
    #pragma unroll
    for (int q = 0; q < 8; q++) {
      const unsigned int vv[4] = {v[q].x, v[q].y, v[q].z, v[q].w};
      #pragma unroll
      for (int e = 0; e < 4; e++) {
        unsigned int val = vv[e];
        if ((val & pmask) == prefix) {
          unsigned int bin = (val >> shift) & 255u;
          if (bin) atomicAdd(&h[bin], 1u);
          else zc++;
        }
      }
    }
    #pragma unroll
    for (int off = 32; off > 0; off >>= 1) zc += __shfl_down(zc, off, 64);
    if (lane == 0) h[0] = zc;
    __threadfence_block();
    // 256-bin suffix scan: lane owns bins [lane*4, lane*4+3]
    const uint4 T = *(const uint4*)&h[lane*4];
    unsigned int s3 = T.w;
    unsigned int s2 = T.z + s3;
    unsigned int s1 = T.y + s2;
    unsigned int s0 = T.x + s1;
    unsigned int tot = s0;
    #pragma unroll
    for (int off = 1; off < 64; off <<= 1) {
      unsigned int y = __shfl_down(tot, off, 64);
      if (lane + off < 64) tot += y;
    }
    const unsigned int ac = tot - s0;    // sum over lanes > lane
    const unsigned int cum[4]   = {s0 + ac, s1 + ac, s2 + ac, s3 + ac};
    const unsigned int above[4] = {s1 + ac, s2 + ac, s3 + ac, ac};
    int fq = -1;
    #pragma unroll
    for (int q = 0; q < 4; q++)
      if (cum[q] >= rem && above[q] < rem) fq = q;
    const unsigned long long mask = __ballot(fq >= 0);
    const int src = (int)(__ffsll((long long)mask) - 1);
    const unsigned int selbin = (fq >= 0) ? (unsigned int)(lane*4 + fq) : 0u;
    const unsigned int nrem   = (fq >= 0) ? (rem - above[fq]) : 0u;
    const unsigned int sel = (unsigned int)__shfl((int)selbin, src, 64);
    rem = (unsigned int)__shfl((int)nrem, src, 64);
    prefix |= (sel << shift);
  }

  const unsigned int amin = prefix;
  float cnt = 0.0f;
  #pragma unroll
  for (int q = 0; q < 8; q++) {
    unsigned int w0 = (v[q].x >= amin) ? v[q].x : 0u;
    unsigned int w1 = (v[q].y >= amin) ? v[q].y : 0u;
    unsigned int w2 = (v[q].z >= amin) ? v[q].z : 0u;
    unsigned int w3 = (v[q].w >= amin) ? v[q].w : 0u;
    float h0 = (w0 != 0u) ? 1.0f : 0.0f;
    float h1 = (w1 != 0u) ? 1.0f : 0.0f;
    float h2 = (w2 != 0u) ? 1.0f : 0.0f;
    float h3 = (w3 != 0u) ? 1.0f : 0.0f;
    cnt += h0 + h1 + h2 + h3;
    ((uint4*)srow)[lane + 64*q] = make_uint4(w0, w1, w2, w3);
    ((float4*)Hrow)[lane + 64*q] = make_float4(h0, h1, h2, h3);
  }
  #pragma unroll
  for (int off = 32; off > 0; off >>= 1) cnt += __shfl_down(cnt, off, 64);
  if (lane == 0) DvOut[row] = 1.0f / (cnt + 1e-10f);
}

// ---------------- column partial sums over o; colH derived from W>0.
__global__ __launch_bounds__(256) void colsum_kernel(
    const float* __restrict__ Wmat,
    float* __restrict__ colH, float* __restrict__ colW)
{
  const int b = blockIdx.z;
  const int i = blockIdx.x * 256 + threadIdx.x;
  const int o0 = blockIdx.y * 64;
  float sh = 0.0f, sw = 0.0f;
  for (int o = 0; o < 64; o++) {
    size_t idx = ((size_t)b * NUM + o0 + o) * NUM + i;
    float w = Wmat[idx];
    sw += w;
    sh += (w > 0.0f) ? 1.0f : 0.0f;
  }
  atomicAdd(&colH[b * NUM + i], sh);
  atomicAdd(&colW[b * NUM + i], sw);
}

// ---------------- De = 1/(colH+eps); W_edge = colW / max(||colW||_2, 1e-12)
__global__ __launch_bounds__(1024) void finalize_kernel(
    const float* __restrict__ colH, const float* __restrict__ colW,
    float* __restrict__ De, float* __restrict__ We)
{
  const int b = blockIdx.x;
  const int t = threadIdx.x;
  float cw[2];
  float sq = 0.0f;
  #pragma unroll
  for (int j = 0; j < 2; j++) {
    int i = t + 1024*j;
    float ch = colH[b * NUM + i];
    De[b * NUM + i] = 1.0f / (ch + 1e-10f);
    cw[j] = colW[b * NUM + i];
    sq += cw[j] * cw[j];
  }
  for (int off = 32; off > 0; off >>= 1) sq += __shfl_down(sq, off, 64);
  __shared__ float red[16];
  __shared__ float s_nrm;
  if ((t & 63) == 0) red[t >> 6] = sq;
  __syncthreads();
  if (t == 0) {
    float tot = 0.0f;
    for (int i2 = 0; i2 < 16; i2++) tot += red[i2];
    s_nrm = fmaxf(sqrtf(tot), 1e-12f);
  }
  __syncthreads();
  #pragma unroll
  for (int j = 0; j < 2; j++)
    We[b * NUM + t + 1024*j] = cw[j] / s_nrm;
}

extern "C" void kernel_launch(void* const* d_in, const int* in_sizes, int n_in,
                              void* d_out, int out_size, void* d_ws, size_t ws_size,
                              hipStream_t stream) {
  const float* H0 = (const float*)d_in[0];
  const float* vf = (const float*)d_in[1];
  const float* ef = (const float*)d_in[2];
  const float* Wq = (const float*)d_in[3];
  const float* bq = (const float*)d_in[4];
  const float* Wk = (const float*)d_in[5];
  const float* bk = (const float*)d_in[6];
  const int* iter = (const int*)d_in[7];

  float* out = (float*)d_out;
  const size_t nH = (size_t)2 * NUM * NUM;
  float* Hout  = out;                 // (2,2048,2048)
  float* Wout  = out + nH;            // (2,2048,2048) — holds score temporarily
  float* DeOut = out + 2 * nH;        // (2,2048,1)
  float* DvOut = DeOut + 2 * NUM;     // (2,2048,1)
  float* WeOut = DvOut + 2 * NUM;     // (2,2048,1)

  float* colH = (float*)d_ws;         // 4096 floats
  float* colW = colH + 2 * NUM;       // 4096 floats

  // fp16 Q/K components (4 x 2MB = 8 MB) live in the H region until topk_apply
  const size_t nC = (size_t)2 * NUM * CDIM;
  unsigned short* base = (unsigned short*)Hout;
  unsigned short* Qhi = base;
  unsigned short* Qlo = base + nC;
  unsigned short* Khi = base + 2 * nC;
  unsigned short* Klo = base + 3 * nC;

  hipMemsetAsync(d_ws, 0, (size_t)2 * 2 * NUM * sizeof(float), stream);

  proj_kernel<<<dim3(NUM/64, CDIM/64, 4), 256, 0, stream>>>(
      Wq, bq, Wk, bk, vf, ef, Qhi, Qlo, Khi, Klo);
  score_kernel<<<dim3(NUM/128, NUM/128, 2), 512, 0, stream>>>(
      Qhi, Qlo, Khi, Klo, H0, Wout);
  topk_apply_kernel<<<dim3(NUM/2), 256, 0, stream>>>(Wout, Hout, iter, DvOut);
  colsum_kernel<<<dim3(NUM/256, NUM/64, 2), 256, 0, stream>>>(Wout, colH, colW);
  finalize_kernel<<<dim3(2), 1024, 0, stream>>>(colH, colW, DeOut, WeOut);
}

// Round 2
// 198.512 us; speedup vs baseline: 1.5994x; 1.5994x over previous
//
#include <hip/hip_runtime.h>
#include <math.h>

#define NUM 2048
#define CDIM 256
#define NUM_LAYER 4

typedef _Float16 f16x8 __attribute__((ext_vector_type(8)));
typedef unsigned short u16x8 __attribute__((ext_vector_type(8)));
typedef float f32x4 __attribute__((ext_vector_type(4)));

// 2-way fp16 split: x = hi + lo + eps, |eps| <= |x| * 2^-23 (11+11 mantissa bits).
static __device__ __forceinline__ void split_f16(float x, unsigned short& h,
                                                 unsigned short& l) {
  _Float16 hi = (_Float16)x;           // RNE
  float r = x - (float)hi;             // exact
  _Float16 lo = (_Float16)r;
  h = __builtin_bit_cast(unsigned short, hi);
  l = __builtin_bit_cast(unsigned short, lo);
}

// ---------------- projection + fp16 2-way split (x = hi + lo). Epilogue
// transposes through LDS so component stores are coalesced.
__global__ __launch_bounds__(256) void proj_kernel(
    const float* __restrict__ Wq, const float* __restrict__ bq,
    const float* __restrict__ Wk, const float* __restrict__ bk,
    const float* __restrict__ vf, const float* __restrict__ ef,
    unsigned short* __restrict__ Qhi, unsigned short* __restrict__ Qlo,
    unsigned short* __restrict__ Khi, unsigned short* __restrict__ Klo)
{
  const int z = blockIdx.z;
  const int b = z >> 1, mm2 = z & 1;
  const float* __restrict__ Wmat = mm2 ? Wk : Wq;
  const float* __restrict__ bias = mm2 ? bk : bq;
  const float* __restrict__ x = (mm2 ? ef : vf) + (size_t)b * CDIM * NUM;
  unsigned short* __restrict__ ohi = mm2 ? Khi : Qhi;
  unsigned short* __restrict__ olo = mm2 ? Klo : Qlo;

  const int n0 = blockIdx.x * 64;
  const int o0 = blockIdx.y * 64;
  __shared__ float Xs[32][65];
  __shared__ float Ws[64][33];
  __shared__ float T[64][69];
  const int t = threadIdx.x;
  const int tx = t & 15, ty = t >> 4;

  float acc[4][4];
  #pragma unroll
  for (int a = 0; a < 4; a++)
    #pragma unroll
    for (int c = 0; c < 4; c++) acc[a][c] = 0.0f;

  for (int cc = 0; cc < CDIM; cc += 32) {
    #pragma unroll
    for (int e = 0; e < 2; e++) {
      int f = t * 2 + e;
      int row = f >> 4, c4 = f & 15;
      const float4 v = *(const float4*)(&x[(size_t)(cc + row) * NUM + n0 + c4 * 4]);
      Xs[row][c4*4+0] = v.x; Xs[row][c4*4+1] = v.y;
      Xs[row][c4*4+2] = v.z; Xs[row][c4*4+3] = v.w;
    }
    #pragma unroll
    for (int e = 0; e < 2; e++) {
      int f = t * 2 + e;
      int row = f >> 3, c4 = f & 7;
      const float4 v = *(const float4*)(&Wmat[(size_t)(o0 + row) * CDIM + cc + c4 * 4]);
      Ws[row][c4*4+0] = v.x; Ws[row][c4*4+1] = v.y;
      Ws[row][c4*4+2] = v.z; Ws[row][c4*4+3] = v.w;
    }
    __syncthreads();
    #pragma unroll
    for (int kk = 0; kk < 32; kk++) {
      float xv[4], wv[4];
      #pragma unroll
      for (int j = 0; j < 4; j++) xv[j] = Xs[kk][tx*4+j];
      #pragma unroll
      for (int j = 0; j < 4; j++) wv[j] = Ws[ty*4+j][kk];
      #pragma unroll
      for (int oi = 0; oi < 4; oi++)
        #pragma unroll
        for (int ni = 0; ni < 4; ni++)
          acc[oi][ni] = fmaf(wv[oi], xv[ni], acc[oi][ni]);
    }
    __syncthreads();
  }
  float bb[4];
  #pragma unroll
  for (int oi = 0; oi < 4; oi++) bb[oi] = bias[o0 + ty*4 + oi];
  #pragma unroll
  for (int ni = 0; ni < 4; ni++)
    #pragma unroll
    for (int oi = 0; oi < 4; oi++)
      T[tx*4+ni][ty*4+oi] = acc[oi][ni] + bb[oi];
  __syncthreads();
  const int n_l = t >> 2;
  const int oc  = (t & 3) * 16;
  float xv[16];
  #pragma unroll
  for (int j = 0; j < 16; j++) xv[j] = T[n_l][oc + j];
  unsigned short hi[16], lo[16];
  #pragma unroll
  for (int j = 0; j < 16; j++) split_f16(xv[j], hi[j], lo[j]);
  const size_t gb = ((size_t)b * NUM + n0 + n_l) * CDIM + o0 + oc;
  *(u16x8*)&ohi[gb]   = *(u16x8*)&hi[0];
  *(u16x8*)&ohi[gb+8] = *(u16x8*)&hi[8];
  *(u16x8*)&olo[gb]   = *(u16x8*)&lo[0];
  *(u16x8*)&olo[gb+8] = *(u16x8*)&lo[8];
}

// ---------------- score via MFMA (fp16 2-way split, 3 products hh+hl+lh:
// 22-bit effective mantissa). 512 threads / 8 waves, 128x128 tile, wave tile
// 64(o)x32(i), stride-36 LDS, reg-prefetch next head.
// launch_bounds (512,2): VGPR budget 256 — (512,6) forced 40 VGPRs and
// spilled accumulators to scratch (R1: +420MB HBM traffic, 3x slower).
__global__ __launch_bounds__(512, 2) void score_kernel(
    const unsigned short* __restrict__ Qhi, const unsigned short* __restrict__ Qlo,
    const unsigned short* __restrict__ Khi, const unsigned short* __restrict__ Klo,
    const float* __restrict__ H0, float* __restrict__ score)
{
  const int b = blockIdx.z;
  const int i0 = blockIdx.x * 128;
  const int o0 = blockIdx.y * 128;
  const int t = threadIdx.x, lane = t & 63, wave = t >> 6;
  const int m = lane & 15, quad = lane >> 4;
  const int obl = (wave & 1) * 64;
  const int ibl = (wave >> 1) * 32;

  __shared__ unsigned short qsh[2][128][36];
  __shared__ unsigned short ksh[2][128][36];

  const int srow = t >> 2;
  const int schk = (t & 3) * 8;

  f32x4 ssum[4][2];
  #pragma unroll
  for (int a = 0; a < 4; a++)
    #pragma unroll
    for (int c = 0; c < 2; c++) ssum[a][c] = (f32x4){0.f, 0.f, 0.f, 0.f};

  const float SC = -1.4426950408889634f * 0.17677669529663687f;  // -log2(e)/sqrt(32)

  u16x8 pq[2], pk[2];
  {
    const size_t go = ((size_t)b * NUM + o0 + srow) * CDIM + schk;
    const size_t gi = ((size_t)b * NUM + i0 + srow) * CDIM + schk;
    pq[0] = *(const u16x8*)&Qhi[go];
    pq[1] = *(const u16x8*)&Qlo[go];
    pk[0] = *(const u16x8*)&Khi[gi];
    pk[1] = *(const u16x8*)&Klo[gi];
  }

  for (int h = 0; h < 8; h++) {
    __syncthreads();
    #pragma unroll
    for (int cp = 0; cp < 2; cp++) {
      *(u16x8*)&qsh[cp][srow][schk] = pq[cp];
      *(u16x8*)&ksh[cp][srow][schk] = pk[cp];
    }
    __syncthreads();
    if (h < 7) {
      const int coff = (h + 1) * 32;
      const size_t go = ((size_t)b * NUM + o0 + srow) * CDIM + coff + schk;
      const size_t gi = ((size_t)b * NUM + i0 + srow) * CDIM + coff + schk;
      pq[0] = *(const u16x8*)&Qhi[go];
      pq[1] = *(const u16x8*)&Qlo[go];
      pk[0] = *(const u16x8*)&Khi[gi];
      pk[1] = *(const u16x8*)&Klo[gi];
    }
    f16x8 a[4][2];
    #pragma unroll
    for (int ot = 0; ot < 4; ot++)
      #pragma unroll
      for (int cp = 0; cp < 2; cp++)
        a[ot][cp] = *(const f16x8*)&qsh[cp][obl + ot*16 + m][quad*8];
    #pragma unroll
    for (int it = 0; it < 2; it++) {
      const f16x8 b0 = *(const f16x8*)&ksh[0][ibl + it*16 + m][quad*8];
      const f16x8 b1 = *(const f16x8*)&ksh[1][ibl + it*16 + m][quad*8];
      #pragma unroll
      for (int ot = 0; ot < 4; ot++) {
        f32x4 c = (f32x4){0.f, 0.f, 0.f, 0.f};
        c = __builtin_amdgcn_mfma_f32_16x16x32_f16(a[ot][0], b0, c, 0, 0, 0); // hh
        c = __builtin_amdgcn_mfma_f32_16x16x32_f16(a[ot][0], b1, c, 0, 0, 0); // hl
        c = __builtin_amdgcn_mfma_f32_16x16x32_f16(a[ot][1], b0, c, 0, 0, 0); // lh
        #pragma unroll
        for (int r = 0; r < 4; r++)
          ssum[ot][it][r] += __builtin_amdgcn_rcpf(1.0f + __builtin_amdgcn_exp2f(c[r] * SC));
      }
    }
  }
  const int ob = o0 + obl, ib = i0 + ibl;
  #pragma unroll
  for (int ot = 0; ot < 4; ot++)
    #pragma unroll
    for (int it = 0; it < 2; it++)
      #pragma unroll
      for (int r = 0; r < 4; r++) {
        const int row = ob + ot*16 + quad*4 + r;
        const int col = ib + it*16 + m;
        const size_t idx = ((size_t)b * NUM + row) * NUM + col;
        score[idx] = H0[idx] * ssum[ot][it][r] * 0.125f;
      }
}

// ---------------- barrier-free fused topk+apply: ONE WAVE PER ROW.
__global__ __launch_bounds__(256) void topk_apply_kernel(
    float* __restrict__ scoreW, float* __restrict__ Hout,
    const int* __restrict__ iterp, float* __restrict__ DvOut)
{
  const int wave = threadIdx.x >> 6, lane = threadIdx.x & 63;
  const int row = blockIdx.x * 4 + wave;
  __shared__ unsigned int hist_all[4][256];
  unsigned int* __restrict__ h = hist_all[wave];
  unsigned int* __restrict__ srow = (unsigned int*)scoreW + (size_t)row * NUM;
  float* __restrict__ Hrow = Hout + (size_t)row * NUM;

  uint4 v[8];
  #pragma unroll
  for (int q = 0; q < 8; q++) v[q] = ((const uint4*)srow)[lane + 64*q];

  const int it = iterp[0];
  int k = (int)((double)NUM * 0.1 * (double)(NUM_LAYER - 1 - it) + 0.5);
  if (k < 1) k = 1;
  if (k > NUM) k = NUM;

  unsigned int prefix = 0;
  unsigned int rem = (unsigned int)k;

  for (int pass = 3; pass >= 0; pass--) {
    const int shift = pass * 8;
    const unsigned int pmask = (pass == 3) ? 0u : (0xFFFFFFFFu << (shift + 8));
    *(uint4*)&h[lane*4] = make_uint4(0u, 0u, 0u, 0u);
    __threadfence_block();
    unsigned int zc = 0;
    #pragma unroll
    for (int q = 0; q < 8; q++) {
      const unsigned int vv[4] = {v[q].x, v[q].y, v[q].z, v[q].w};
      #pragma unroll
      for (int e = 0; e < 4; e++) {
        unsigned int val = vv[e];
        if ((val & pmask) == prefix) {
          unsigned int bin = (val >> shift) & 255u;
          if (bin) atomicAdd(&h[bin], 1u);
          else zc++;
        }
      }
    }
    #pragma unroll
    for (int off = 32; off > 0; off >>= 1) zc += __shfl_down(zc, off, 64);
    if (lane == 0) h[0] = zc;
    __threadfence_block();
    // 256-bin suffix scan: lane owns bins [lane*4, lane*4+3]
    const uint4 T = *(const uint4*)&h[lane*4];
    unsigned int s3 = T.w;
    unsigned int s2 = T.z + s3;
    unsigned int s1 = T.y + s2;
    unsigned int s0 = T.x + s1;
    unsigned int tot = s0;
    #pragma unroll
    for (int off = 1; off < 64; off <<= 1) {
      unsigned int y = __shfl_down(tot, off, 64);
      if (lane + off < 64) tot += y;
    }
    const unsigned int ac = tot - s0;    // sum over lanes > lane
    const unsigned int cum[4]   = {s0 + ac, s1 + ac, s2 + ac, s3 + ac};
    const unsigned int above[4] = {s1 + ac, s2 + ac, s3 + ac, ac};
    int fq = -1;
    #pragma unroll
    for (int q = 0; q < 4; q++)
      if (cum[q] >= rem && above[q] < rem) fq = q;
    const unsigned long long mask = __ballot(fq >= 0);
    const int src = (int)(__ffsll((long long)mask) - 1);
    const unsigned int selbin = (fq >= 0) ? (unsigned int)(lane*4 + fq) : 0u;
    const unsigned int nrem   = (fq >= 0) ? (rem - above[fq]) : 0u;
    const unsigned int sel = (unsigned int)__shfl((int)selbin, src, 64);
    rem = (unsigned int)__shfl((int)nrem, src, 64);
    prefix |= (sel << shift);
  }

  const unsigned int amin = prefix;
  float cnt = 0.0f;
  #pragma unroll
  for (int q = 0; q < 8; q++) {
    unsigned int w0 = (v[q].x >= amin) ? v[q].x : 0u;
    unsigned int w1 = (v[q].y >= amin) ? v[q].y : 0u;
    unsigned int w2 = (v[q].z >= amin) ? v[q].z : 0u;
    unsigned int w3 = (v[q].w >= amin) ? v[q].w : 0u;
    float h0 = (w0 != 0u) ? 1.0f : 0.0f;
    float h1 = (w1 != 0u) ? 1.0f : 0.0f;
    float h2 = (w2 != 0u) ? 1.0f : 0.0f;
    float h3 = (w3 != 0u) ? 1.0f : 0.0f;
    cnt += h0 + h1 + h2 + h3;
    ((uint4*)srow)[lane + 64*q] = make_uint4(w0, w1, w2, w3);
    ((float4*)Hrow)[lane + 64*q] = make_float4(h0, h1, h2, h3);
  }
  #pragma unroll
  for (int off = 32; off > 0; off >>= 1) cnt += __shfl_down(cnt, off, 64);
  if (lane == 0) DvOut[row] = 1.0f / (cnt + 1e-10f);
}

// ---------------- column partial sums over o; colH derived from W>0.
__global__ __launch_bounds__(256) void colsum_kernel(
    const float* __restrict__ Wmat,
    float* __restrict__ colH, float* __restrict__ colW)
{
  const int b = blockIdx.z;
  const int i = blockIdx.x * 256 + threadIdx.x;
  const int o0 = blockIdx.y * 64;
  float sh = 0.0f, sw = 0.0f;
  for (int o = 0; o < 64; o++) {
    size_t idx = ((size_t)b * NUM + o0 + o) * NUM + i;
    float w = Wmat[idx];
    sw += w;
    sh += (w > 0.0f) ? 1.0f : 0.0f;
  }
  atomicAdd(&colH[b * NUM + i], sh);
  atomicAdd(&colW[b * NUM + i], sw);
}

// ---------------- De = 1/(colH+eps); W_edge = colW / max(||colW||_2, 1e-12)
__global__ __launch_bounds__(1024) void finalize_kernel(
    const float* __restrict__ colH, const float* __restrict__ colW,
    float* __restrict__ De, float* __restrict__ We)
{
  const int b = blockIdx.x;
  const int t = threadIdx.x;
  float cw[2];
  float sq = 0.0f;
  #pragma unroll
  for (int j = 0; j < 2; j++) {
    int i = t + 1024*j;
    float ch = colH[b * NUM + i];
    De[b * NUM + i] = 1.0f / (ch + 1e-10f);
    cw[j] = colW[b * NUM + i];
    sq += cw[j] * cw[j];
  }
  for (int off = 32; off > 0; off >>= 1) sq += __shfl_down(sq, off, 64);
  __shared__ float red[16];
  __shared__ float s_nrm;
  if ((t & 63) == 0) red[t >> 6] = sq;
  __syncthreads();
  if (t == 0) {
    float tot = 0.0f;
    for (int i2 = 0; i2 < 16; i2++) tot += red[i2];
    s_nrm = fmaxf(sqrtf(tot), 1e-12f);
  }
  __syncthreads();
  #pragma unroll
  for (int j = 0; j < 2; j++)
    We[b * NUM + t + 1024*j] = cw[j] / s_nrm;
}

extern "C" void kernel_launch(void* const* d_in, const int* in_sizes, int n_in,
                              void* d_out, int out_size, void* d_ws, size_t ws_size,
                              hipStream_t stream) {
  const float* H0 = (const float*)d_in[0];
  const float* vf = (const float*)d_in[1];
  const float* ef = (const float*)d_in[2];
  const float* Wq = (const float*)d_in[3];
  const float* bq = (const float*)d_in[4];
  const float* Wk = (const float*)d_in[5];
  const float* bk = (const float*)d_in[6];
  const int* iter = (const int*)d_in[7];

  float* out = (float*)d_out;
  const size_t nH = (size_t)2 * NUM * NUM;
  float* Hout  = out;                 // (2,2048,2048)
  float* Wout  = out + nH;            // (2,2048,2048) — holds score temporarily
  float* DeOut = out + 2 * nH;        // (2,2048,1)
  float* DvOut = DeOut + 2 * NUM;     // (2,2048,1)
  float* WeOut = DvOut + 2 * NUM;     // (2,2048,1)

  float* colH = (float*)d_ws;         // 4096 floats
  float* colW = colH + 2 * NUM;       // 4096 floats

  // fp16 Q/K components (4 x 2MB = 8 MB) live in the H region until topk_apply
  const size_t nC = (size_t)2 * NUM * CDIM;
  unsigned short* base = (unsigned short*)Hout;
  unsigned short* Qhi = base;
  unsigned short* Qlo = base + nC;
  unsigned short* Khi = base + 2 * nC;
  unsigned short* Klo = base + 3 * nC;

  hipMemsetAsync(d_ws, 0, (size_t)2 * 2 * NUM * sizeof(float), stream);

  proj_kernel<<<dim3(NUM/64, CDIM/64, 4), 256, 0, stream>>>(
      Wq, bq, Wk, bk, vf, ef, Qhi, Qlo, Khi, Klo);
  score_kernel<<<dim3(NUM/128, NUM/128, 2), 512, 0, stream>>>(
      Qhi, Qlo, Khi, Klo, H0, Wout);
  topk_apply_kernel<<<dim3(NUM/2), 256, 0, stream>>>(Wout, Hout, iter, DvOut);
  colsum_kernel<<<dim3(NUM/256, NUM/64, 2), 256, 0, stream>>>(Wout, colH, colW);
  finalize_kernel<<<dim3(2), 1024, 0, stream>>>(colH, colW, DeOut, WeOut);
}

// Round 3
// 196.095 us; speedup vs baseline: 1.6191x; 1.0123x over previous
//
#include <hip/hip_runtime.h>
#include <math.h>

#define NUM 2048
#define CDIM 256
#define NUM_LAYER 4

typedef _Float16 f16x8 __attribute__((ext_vector_type(8)));
typedef unsigned short u16x8 __attribute__((ext_vector_type(8)));
typedef float f32x4 __attribute__((ext_vector_type(4)));

// 2-way fp16 split: x = hi + lo + eps, |eps| <= |x| * 2^-23 (11+11 mantissa bits).
static __device__ __forceinline__ void split_f16(float x, unsigned short& h,
                                                 unsigned short& l) {
  _Float16 hi = (_Float16)x;           // RNE
  float r = x - (float)hi;             // exact
  _Float16 lo = (_Float16)r;
  h = __builtin_bit_cast(unsigned short, hi);
  l = __builtin_bit_cast(unsigned short, lo);
}

// ---------------- projection + fp16 2-way split (x = hi + lo). Epilogue
// transposes through LDS so component stores are coalesced.
__global__ __launch_bounds__(256) void proj_kernel(
    const float* __restrict__ Wq, const float* __restrict__ bq,
    const float* __restrict__ Wk, const float* __restrict__ bk,
    const float* __restrict__ vf, const float* __restrict__ ef,
    unsigned short* __restrict__ Qhi, unsigned short* __restrict__ Qlo,
    unsigned short* __restrict__ Khi, unsigned short* __restrict__ Klo)
{
  const int z = blockIdx.z;
  const int b = z >> 1, mm2 = z & 1;
  const float* __restrict__ Wmat = mm2 ? Wk : Wq;
  const float* __restrict__ bias = mm2 ? bk : bq;
  const float* __restrict__ x = (mm2 ? ef : vf) + (size_t)b * CDIM * NUM;
  unsigned short* __restrict__ ohi = mm2 ? Khi : Qhi;
  unsigned short* __restrict__ olo = mm2 ? Klo : Qlo;

  const int n0 = blockIdx.x * 64;
  const int o0 = blockIdx.y * 64;
  __shared__ float Xs[32][65];
  __shared__ float Ws[64][33];
  __shared__ float T[64][69];
  const int t = threadIdx.x;
  const int tx = t & 15, ty = t >> 4;

  float acc[4][4];
  #pragma unroll
  for (int a = 0; a < 4; a++)
    #pragma unroll
    for (int c = 0; c < 4; c++) acc[a][c] = 0.0f;

  for (int cc = 0; cc < CDIM; cc += 32) {
    #pragma unroll
    for (int e = 0; e < 2; e++) {
      int f = t * 2 + e;
      int row = f >> 4, c4 = f & 15;
      const float4 v = *(const float4*)(&x[(size_t)(cc + row) * NUM + n0 + c4 * 4]);
      Xs[row][c4*4+0] = v.x; Xs[row][c4*4+1] = v.y;
      Xs[row][c4*4+2] = v.z; Xs[row][c4*4+3] = v.w;
    }
    #pragma unroll
    for (int e = 0; e < 2; e++) {
      int f = t * 2 + e;
      int row = f >> 3, c4 = f & 7;
      const float4 v = *(const float4*)(&Wmat[(size_t)(o0 + row) * CDIM + cc + c4 * 4]);
      Ws[row][c4*4+0] = v.x; Ws[row][c4*4+1] = v.y;
      Ws[row][c4*4+2] = v.z; Ws[row][c4*4+3] = v.w;
    }
    __syncthreads();
    #pragma unroll
    for (int kk = 0; kk < 32; kk++) {
      float xv[4], wv[4];
      #pragma unroll
      for (int j = 0; j < 4; j++) xv[j] = Xs[kk][tx*4+j];
      #pragma unroll
      for (int j = 0; j < 4; j++) wv[j] = Ws[ty*4+j][kk];
      #pragma unroll
      for (int oi = 0; oi < 4; oi++)
        #pragma unroll
        for (int ni = 0; ni < 4; ni++)
          acc[oi][ni] = fmaf(wv[oi], xv[ni], acc[oi][ni]);
    }
    __syncthreads();
  }
  float bb[4];
  #pragma unroll
  for (int oi = 0; oi < 4; oi++) bb[oi] = bias[o0 + ty*4 + oi];
  #pragma unroll
  for (int ni = 0; ni < 4; ni++)
    #pragma unroll
    for (int oi = 0; oi < 4; oi++)
      T[tx*4+ni][ty*4+oi] = acc[oi][ni] + bb[oi];
  __syncthreads();
  const int n_l = t >> 2;
  const int oc  = (t & 3) * 16;
  float xv[16];
  #pragma unroll
  for (int j = 0; j < 16; j++) xv[j] = T[n_l][oc + j];
  unsigned short hi[16], lo[16];
  #pragma unroll
  for (int j = 0; j < 16; j++) split_f16(xv[j], hi[j], lo[j]);
  const size_t gb = ((size_t)b * NUM + n0 + n_l) * CDIM + o0 + oc;
  *(u16x8*)&ohi[gb]   = *(u16x8*)&hi[0];
  *(u16x8*)&ohi[gb+8] = *(u16x8*)&hi[8];
  *(u16x8*)&olo[gb]   = *(u16x8*)&lo[0];
  *(u16x8*)&olo[gb+8] = *(u16x8*)&lo[8];
}

// ---------------- score via MFMA (fp16 2-way split, 3 products hh+hl+lh).
// R3 restructure: double-buffered LDS, ONE __syncthreads per head (was 2),
// prefetch issued AFTER the barrier (the barrier drains vmcnt, so loads
// issued before it gain nothing), and NO H0 read (mask moved to topk) so
// the epilogue is pure streaming stores. LDS 73.7KB -> 2 blocks/CU.
__global__ __launch_bounds__(512, 2) void score_kernel(
    const unsigned short* __restrict__ Qhi, const unsigned short* __restrict__ Qlo,
    const unsigned short* __restrict__ Khi, const unsigned short* __restrict__ Klo,
    float* __restrict__ score)
{
  const int b = blockIdx.z;
  const int i0 = blockIdx.x * 128;
  const int o0 = blockIdx.y * 128;
  const int t = threadIdx.x, lane = t & 63, wave = t >> 6;
  const int m = lane & 15, quad = lane >> 4;
  const int obl = (wave & 1) * 64;
  const int ibl = (wave >> 1) * 32;

  __shared__ unsigned short qsh[2][2][128][36];  // [buf][comp][row][col]
  __shared__ unsigned short ksh[2][2][128][36];

  const int srow = t >> 2;
  const int schk = (t & 3) * 8;
  const size_t gq = ((size_t)b * NUM + o0 + srow) * CDIM + schk;
  const size_t gk = ((size_t)b * NUM + i0 + srow) * CDIM + schk;

  f32x4 ssum[4][2];
  #pragma unroll
  for (int a = 0; a < 4; a++)
    #pragma unroll
    for (int c = 0; c < 2; c++) ssum[a][c] = (f32x4){0.f, 0.f, 0.f, 0.f};

  const float SC = -1.4426950408889634f * 0.17677669529663687f;  // -log2(e)/sqrt(32)

  u16x8 pq[2], pk[2];
  // prologue: head 0 -> buf 0
  pq[0] = *(const u16x8*)&Qhi[gq];
  pq[1] = *(const u16x8*)&Qlo[gq];
  pk[0] = *(const u16x8*)&Khi[gk];
  pk[1] = *(const u16x8*)&Klo[gk];
  *(u16x8*)&qsh[0][0][srow][schk] = pq[0];
  *(u16x8*)&qsh[0][1][srow][schk] = pq[1];
  *(u16x8*)&ksh[0][0][srow][schk] = pk[0];
  *(u16x8*)&ksh[0][1][srow][schk] = pk[1];
  __syncthreads();
  // prefetch head 1 (hidden under compute of head 0)
  pq[0] = *(const u16x8*)&Qhi[gq + 32];
  pq[1] = *(const u16x8*)&Qlo[gq + 32];
  pk[0] = *(const u16x8*)&Khi[gk + 32];
  pk[1] = *(const u16x8*)&Klo[gk + 32];

  for (int h = 0; h < 8; h++) {
    const int c = h & 1;
    f16x8 a[4][2];
    #pragma unroll
    for (int ot = 0; ot < 4; ot++)
      #pragma unroll
      for (int cp = 0; cp < 2; cp++)
        a[ot][cp] = *(const f16x8*)&qsh[c][cp][obl + ot*16 + m][quad*8];
    #pragma unroll
    for (int it = 0; it < 2; it++) {
      const f16x8 b0 = *(const f16x8*)&ksh[c][0][ibl + it*16 + m][quad*8];
      const f16x8 b1 = *(const f16x8*)&ksh[c][1][ibl + it*16 + m][quad*8];
      #pragma unroll
      for (int ot = 0; ot < 4; ot++) {
        f32x4 cc = (f32x4){0.f, 0.f, 0.f, 0.f};
        cc = __builtin_amdgcn_mfma_f32_16x16x32_f16(a[ot][0], b0, cc, 0, 0, 0); // hh
        cc = __builtin_amdgcn_mfma_f32_16x16x32_f16(a[ot][0], b1, cc, 0, 0, 0); // hl
        cc = __builtin_amdgcn_mfma_f32_16x16x32_f16(a[ot][1], b0, cc, 0, 0, 0); // lh
        #pragma unroll
        for (int r = 0; r < 4; r++)
          ssum[ot][it][r] += __builtin_amdgcn_rcpf(1.0f + __builtin_amdgcn_exp2f(cc[r] * SC));
      }
    }
    if (h < 7) {
      // stage head h+1 into the other buffer, one barrier, then prefetch h+2
      *(u16x8*)&qsh[c^1][0][srow][schk] = pq[0];
      *(u16x8*)&qsh[c^1][1][srow][schk] = pq[1];
      *(u16x8*)&ksh[c^1][0][srow][schk] = pk[0];
      *(u16x8*)&ksh[c^1][1][srow][schk] = pk[1];
      __syncthreads();
      if (h < 6) {
        const size_t co = (size_t)(h + 2) * 32;
        pq[0] = *(const u16x8*)&Qhi[gq + co];
        pq[1] = *(const u16x8*)&Qlo[gq + co];
        pk[0] = *(const u16x8*)&Khi[gk + co];
        pk[1] = *(const u16x8*)&Klo[gk + co];
      }
    }
  }

  const int ob = o0 + obl, ib = i0 + ibl;
  #pragma unroll
  for (int ot = 0; ot < 4; ot++)
    #pragma unroll
    for (int it = 0; it < 2; it++)
      #pragma unroll
      for (int r = 0; r < 4; r++) {
        const int row = ob + ot*16 + quad*4 + r;
        const int col = ib + it*16 + m;
        const size_t idx = ((size_t)b * NUM + row) * NUM + col;
        score[idx] = ssum[ot][it][r] * 0.125f;
      }
}

// ---------------- barrier-free fused topk+apply: ONE WAVE PER ROW.
// Now also applies the H0 mask (moved out of score_kernel): v = H0 ? score : 0.
__global__ __launch_bounds__(256) void topk_apply_kernel(
    float* __restrict__ scoreW, const float* __restrict__ H0,
    float* __restrict__ Hout, const int* __restrict__ iterp,
    float* __restrict__ DvOut)
{
  const int wave = threadIdx.x >> 6, lane = threadIdx.x & 63;
  const int row = blockIdx.x * 4 + wave;
  __shared__ unsigned int hist_all[4][256];
  unsigned int* __restrict__ h = hist_all[wave];
  unsigned int* __restrict__ srow = (unsigned int*)scoreW + (size_t)row * NUM;
  const float* __restrict__ h0row = H0 + (size_t)row * NUM;
  float* __restrict__ Hrow = Hout + (size_t)row * NUM;

  uint4 v[8];
  #pragma unroll
  for (int q = 0; q < 8; q++) {
    const uint4 s4 = ((const uint4*)srow)[lane + 64*q];
    const float4 m4 = ((const float4*)h0row)[lane + 64*q];
    v[q].x = (m4.x != 0.0f) ? s4.x : 0u;
    v[q].y = (m4.y != 0.0f) ? s4.y : 0u;
    v[q].z = (m4.z != 0.0f) ? s4.z : 0u;
    v[q].w = (m4.w != 0.0f) ? s4.w : 0u;
  }

  const int it = iterp[0];
  int k = (int)((double)NUM * 0.1 * (double)(NUM_LAYER - 1 - it) + 0.5);
  if (k < 1) k = 1;
  if (k > NUM) k = NUM;

  unsigned int prefix = 0;
  unsigned int rem = (unsigned int)k;

  for (int pass = 3; pass >= 0; pass--) {
    const int shift = pass * 8;
    const unsigned int pmask = (pass == 3) ? 0u : (0xFFFFFFFFu << (shift + 8));
    *(uint4*)&h[lane*4] = make_uint4(0u, 0u, 0u, 0u);
    __threadfence_block();
    unsigned int zc = 0;
    #pragma unroll
    for (int q = 0; q < 8; q++) {
      const unsigned int vv[4] = {v[q].x, v[q].y, v[q].z, v[q].w};
      #pragma unroll
      for (int e = 0; e < 4; e++) {
        unsigned int val = vv[e];
        if ((val & pmask) == prefix) {
          unsigned int bin = (val >> shift) & 255u;
          if (bin) atomicAdd(&h[bin], 1u);
          else zc++;
        }
      }
    }
    #pragma unroll
    for (int off = 32; off > 0; off >>= 1) zc += __shfl_down(zc, off, 64);
    if (lane == 0) h[0] = zc;
    __threadfence_block();
    // 256-bin suffix scan: lane owns bins [lane*4, lane*4+3]
    const uint4 T = *(const uint4*)&h[lane*4];
    unsigned int s3 = T.w;
    unsigned int s2 = T.z + s3;
    unsigned int s1 = T.y + s2;
    unsigned int s0 = T.x + s1;
    unsigned int tot = s0;
    #pragma unroll
    for (int off = 1; off < 64; off <<= 1) {
      unsigned int y = __shfl_down(tot, off, 64);
      if (lane + off < 64) tot += y;
    }
    const unsigned int ac = tot - s0;    // sum over lanes > lane
    const unsigned int cum[4]   = {s0 + ac, s1 + ac, s2 + ac, s3 + ac};
    const unsigned int above[4] = {s1 + ac, s2 + ac, s3 + ac, ac};
    int fq = -1;
    #pragma unroll
    for (int q = 0; q < 4; q++)
      if (cum[q] >= rem && above[q] < rem) fq = q;
    const unsigned long long mask = __ballot(fq >= 0);
    const int src = (int)(__ffsll((long long)mask) - 1);
    const unsigned int selbin = (fq >= 0) ? (unsigned int)(lane*4 + fq) : 0u;
    const unsigned int nrem   = (fq >= 0) ? (rem - above[fq]) : 0u;
    const unsigned int sel = (unsigned int)__shfl((int)selbin, src, 64);
    rem = (unsigned int)__shfl((int)nrem, src, 64);
    prefix |= (sel << shift);
  }

  const unsigned int amin = prefix;
  float cnt = 0.0f;
  #pragma unroll
  for (int q = 0; q < 8; q++) {
    unsigned int w0 = (v[q].x >= amin) ? v[q].x : 0u;
    unsigned int w1 = (v[q].y >= amin) ? v[q].y : 0u;
    unsigned int w2 = (v[q].z >= amin) ? v[q].z : 0u;
    unsigned int w3 = (v[q].w >= amin) ? v[q].w : 0u;
    float h0 = (w0 != 0u) ? 1.0f : 0.0f;
    float h1 = (w1 != 0u) ? 1.0f : 0.0f;
    float h2 = (w2 != 0u) ? 1.0f : 0.0f;
    float h3 = (w3 != 0u) ? 1.0f : 0.0f;
    cnt += h0 + h1 + h2 + h3;
    ((uint4*)srow)[lane + 64*q] = make_uint4(w0, w1, w2, w3);
    ((float4*)Hrow)[lane + 64*q] = make_float4(h0, h1, h2, h3);
  }
  #pragma unroll
  for (int off = 32; off > 0; off >>= 1) cnt += __shfl_down(cnt, off, 64);
  if (lane == 0) DvOut[row] = 1.0f / (cnt + 1e-10f);
}

// ---------------- column partial sums over o; colH derived from W>0.
__global__ __launch_bounds__(256) void colsum_kernel(
    const float* __restrict__ Wmat,
    float* __restrict__ colH, float* __restrict__ colW)
{
  const int b = blockIdx.z;
  const int i = blockIdx.x * 256 + threadIdx.x;
  const int o0 = blockIdx.y * 64;
  float sh = 0.0f, sw = 0.0f;
  for (int o = 0; o < 64; o++) {
    size_t idx = ((size_t)b * NUM + o0 + o) * NUM + i;
    float w = Wmat[idx];
    sw += w;
    sh += (w > 0.0f) ? 1.0f : 0.0f;
  }
  atomicAdd(&colH[b * NUM + i], sh);
  atomicAdd(&colW[b * NUM + i], sw);
}

// ---------------- De = 1/(colH+eps); W_edge = colW / max(||colW||_2, 1e-12)
__global__ __launch_bounds__(1024) void finalize_kernel(
    const float* __restrict__ colH, const float* __restrict__ colW,
    float* __restrict__ De, float* __restrict__ We)
{
  const int b = blockIdx.x;
  const int t = threadIdx.x;
  float cw[2];
  float sq = 0.0f;
  #pragma unroll
  for (int j = 0; j < 2; j++) {
    int i = t + 1024*j;
    float ch = colH[b * NUM + i];
    De[b * NUM + i] = 1.0f / (ch + 1e-10f);
    cw[j] = colW[b * NUM + i];
    sq += cw[j] * cw[j];
  }
  for (int off = 32; off > 0; off >>= 1) sq += __shfl_down(sq, off, 64);
  __shared__ float red[16];
  __shared__ float s_nrm;
  if ((t & 63) == 0) red[t >> 6] = sq;
  __syncthreads();
  if (t == 0) {
    float tot = 0.0f;
    for (int i2 = 0; i2 < 16; i2++) tot += red[i2];
    s_nrm = fmaxf(sqrtf(tot), 1e-12f);
  }
  __syncthreads();
  #pragma unroll
  for (int j = 0; j < 2; j++)
    We[b * NUM + t + 1024*j] = cw[j] / s_nrm;
}

extern "C" void kernel_launch(void* const* d_in, const int* in_sizes, int n_in,
                              void* d_out, int out_size, void* d_ws, size_t ws_size,
                              hipStream_t stream) {
  const float* H0 = (const float*)d_in[0];
  const float* vf = (const float*)d_in[1];
  const float* ef = (const float*)d_in[2];
  const float* Wq = (const float*)d_in[3];
  const float* bq = (const float*)d_in[4];
  const float* Wk = (const float*)d_in[5];
  const float* bk = (const float*)d_in[6];
  const int* iter = (const int*)d_in[7];

  float* out = (float*)d_out;
  const size_t nH = (size_t)2 * NUM * NUM;
  float* Hout  = out;                 // (2,2048,2048)
  float* Wout  = out + nH;            // (2,2048,2048) — holds score temporarily
  float* DeOut = out + 2 * nH;        // (2,2048,1)
  float* DvOut = DeOut + 2 * NUM;     // (2,2048,1)
  float* WeOut = DvOut + 2 * NUM;     // (2,2048,1)

  float* colH = (float*)d_ws;         // 4096 floats
  float* colW = colH + 2 * NUM;       // 4096 floats

  // fp16 Q/K components (4 x 2MB = 8 MB) live in the H region until topk_apply
  const size_t nC = (size_t)2 * NUM * CDIM;
  unsigned short* base = (unsigned short*)Hout;
  unsigned short* Qhi = base;
  unsigned short* Qlo = base + nC;
  unsigned short* Khi = base + 2 * nC;
  unsigned short* Klo = base + 3 * nC;

  hipMemsetAsync(d_ws, 0, (size_t)2 * 2 * NUM * sizeof(float), stream);

  proj_kernel<<<dim3(NUM/64, CDIM/64, 4), 256, 0, stream>>>(
      Wq, bq, Wk, bk, vf, ef, Qhi, Qlo, Khi, Klo);
  score_kernel<<<dim3(NUM/128, NUM/128, 2), 512, 0, stream>>>(
      Qhi, Qlo, Khi, Klo, Wout);
  topk_apply_kernel<<<dim3(NUM/2), 256, 0, stream>>>(Wout, H0, Hout, iter, DvOut);
  colsum_kernel<<<dim3(NUM/256, NUM/64, 2), 256, 0, stream>>>(Wout, colH, colW);
  finalize_kernel<<<dim3(2), 1024, 0, stream>>>(colH, colW, DeOut, WeOut);
}

// Round 5
// 180.993 us; speedup vs baseline: 1.7542x; 1.0834x over previous
//
#include <hip/hip_runtime.h>
#include <math.h>

#define NUM 2048
#define CDIM 256
#define NUM_LAYER 4

typedef _Float16 f16x8 __attribute__((ext_vector_type(8)));
typedef unsigned short u16x8 __attribute__((ext_vector_type(8)));
typedef float f32x4 __attribute__((ext_vector_type(4)));

// 2-way fp16 split: x = hi + lo + eps, |eps| <= |x| * 2^-23 (11+11 mantissa bits).
static __device__ __forceinline__ void split_f16(float x, unsigned short& h,
                                                 unsigned short& l) {
  _Float16 hi = (_Float16)x;           // RNE
  float r = x - (float)hi;             // exact
  _Float16 lo = (_Float16)r;
  h = __builtin_bit_cast(unsigned short, hi);
  l = __builtin_bit_cast(unsigned short, lo);
}

// Scaled 3-way f16 split: x ~= h + m*2^-11 + l*2^-22, error <= |x|*2^-33
// (below fp32 eps). m,l are residuals PRE-SCALED by 2^11/2^22 so they stay
// f16-normal (no denormal-flush hazard in MFMA); hi is zeroed below f16
// min-normal so tiny x routes into the m component at full precision.
static __device__ __forceinline__ void split3_f16(float x, unsigned short& h,
                                                  unsigned short& m,
                                                  unsigned short& l) {
  float xh = (fabsf(x) >= 6.103515625e-05f) ? x : 0.0f;
  _Float16 hi = (_Float16)xh;
  float r1 = x - (float)hi;            // exact (Dekker split)
  float r1s = r1 * 2048.0f;            // exact pow2 scale
  _Float16 mi = (_Float16)r1s;
  float r2s = (r1s - (float)mi) * 2048.0f;  // exact
  _Float16 lo = (_Float16)r2s;
  h = __builtin_bit_cast(unsigned short, hi);
  m = __builtin_bit_cast(unsigned short, mi);
  l = __builtin_bit_cast(unsigned short, lo);
}

// ---------------- projection via MFMA, fp32-exact-class numerics.
// R5: R4's 2-way proj split (error ~2^-22) flipped a topk selection; this
// version uses the scaled 3-way split with THREE accumulators
// (hh | hm+mh | hl+lh+mm), combined as acc0 + acc1*2^-11 + acc2*2^-22.
// Dropped terms ~2^-33 relative — tighter than the old fp32 FMA loop,
// at ~10x fewer LDS ops (MFMA instead of strided scalar reads).
__global__ __launch_bounds__(256) void proj_kernel(
    const float* __restrict__ Wq, const float* __restrict__ bq,
    const float* __restrict__ Wk, const float* __restrict__ bk,
    const float* __restrict__ vf, const float* __restrict__ ef,
    unsigned short* __restrict__ Qhi, unsigned short* __restrict__ Qlo,
    unsigned short* __restrict__ Khi, unsigned short* __restrict__ Klo)
{
  const int z = blockIdx.z;
  const int b = z >> 1, mm2 = z & 1;
  const float* __restrict__ Wmat = mm2 ? Wk : Wq;
  const float* __restrict__ bias = mm2 ? bk : bq;
  const float* __restrict__ x = (mm2 ? ef : vf) + (size_t)b * CDIM * NUM;
  unsigned short* __restrict__ ohi = mm2 ? Khi : Qhi;
  unsigned short* __restrict__ olo = mm2 ? Klo : Qlo;

  const int n0 = blockIdx.x * 64;
  const int o0 = blockIdx.y * 64;

  __shared__ unsigned short xsh[3][64][36];  // [comp][n][c], pitch 36
  __shared__ unsigned short wsh[3][64][36];  // [comp][o][c]
  __shared__ float T[64][69];                // [n][o] epilogue transpose

  const int t = threadIdx.x, lane = t & 63, wave = t >> 6;
  const int ml = lane & 15, quad = lane >> 4;
  const int nbl = wave * 16;                 // wave's 16-n subtile

  // staging maps
  const int cp = t >> 4;                     // 0..15 -> c pair
  const int nq = t & 15;                     // 0..15 -> n quad
  const int orow = t >> 2;                   // 0..63
  const int cq = (t & 3) * 8;                // 0,8,16,24

  f32x4 acc0[4], acc1[4], acc2[4];
  #pragma unroll
  for (int ot = 0; ot < 4; ot++) {
    acc0[ot] = (f32x4){0.f, 0.f, 0.f, 0.f};
    acc1[ot] = (f32x4){0.f, 0.f, 0.f, 0.f};
    acc2[ot] = (f32x4){0.f, 0.f, 0.f, 0.f};
  }

  for (int cc = 0; cc < CDIM; cc += 32) {
    if (cc) __syncthreads();
    // ---- stage x: 32c x 64n, transpose to [n][c] with 3-way split
    {
      const float4 f4a = *(const float4*)&x[(size_t)(cc + 2*cp) * NUM + n0 + nq*4];
      const float4 f4b = *(const float4*)&x[(size_t)(cc + 2*cp + 1) * NUM + n0 + nq*4];
      const float va[4] = {f4a.x, f4a.y, f4a.z, f4a.w};
      const float vb[4] = {f4b.x, f4b.y, f4b.z, f4b.w};
      #pragma unroll
      for (int j = 0; j < 4; j++) {
        unsigned short h0, m0, l0, h1, m1, l1;
        split3_f16(va[j], h0, m0, l0);
        split3_f16(vb[j], h1, m1, l1);
        *(unsigned*)&xsh[0][nq*4 + j][2*cp] = (unsigned)h0 | ((unsigned)h1 << 16);
        *(unsigned*)&xsh[1][nq*4 + j][2*cp] = (unsigned)m0 | ((unsigned)m1 << 16);
        *(unsigned*)&xsh[2][nq*4 + j][2*cp] = (unsigned)l0 | ((unsigned)l1 << 16);
      }
    }
    // ---- stage W: 64o x 32c, already c-contiguous
    {
      const float4 w0 = *(const float4*)&Wmat[(size_t)(o0 + orow) * CDIM + cc + cq];
      const float4 w1 = *(const float4*)&Wmat[(size_t)(o0 + orow) * CDIM + cc + cq + 4];
      const float wv[8] = {w0.x, w0.y, w0.z, w0.w, w1.x, w1.y, w1.z, w1.w};
      #pragma unroll
      for (int j = 0; j < 4; j++) {
        unsigned short h0, m0, l0, h1, m1, l1;
        split3_f16(wv[2*j],   h0, m0, l0);
        split3_f16(wv[2*j+1], h1, m1, l1);
        *(unsigned*)&wsh[0][orow][cq + 2*j] = (unsigned)h0 | ((unsigned)h1 << 16);
        *(unsigned*)&wsh[1][orow][cq + 2*j] = (unsigned)m0 | ((unsigned)m1 << 16);
        *(unsigned*)&wsh[2][orow][cq + 2*j] = (unsigned)l0 | ((unsigned)l1 << 16);
      }
    }
    __syncthreads();
    // ---- MFMA: A = W rows (o), B = x rows (n); D row<-o, col<-n
    const f16x8 bh = *(const f16x8*)&xsh[0][nbl + ml][quad*8];
    const f16x8 bm = *(const f16x8*)&xsh[1][nbl + ml][quad*8];
    const f16x8 bl = *(const f16x8*)&xsh[2][nbl + ml][quad*8];
    #pragma unroll
    for (int ot = 0; ot < 4; ot++) {
      const f16x8 ah = *(const f16x8*)&wsh[0][ot*16 + ml][quad*8];
      const f16x8 am = *(const f16x8*)&wsh[1][ot*16 + ml][quad*8];
      const f16x8 al = *(const f16x8*)&wsh[2][ot*16 + ml][quad*8];
      acc0[ot] = __builtin_amdgcn_mfma_f32_16x16x32_f16(ah, bh, acc0[ot], 0, 0, 0);
      acc1[ot] = __builtin_amdgcn_mfma_f32_16x16x32_f16(ah, bm, acc1[ot], 0, 0, 0);
      acc1[ot] = __builtin_amdgcn_mfma_f32_16x16x32_f16(am, bh, acc1[ot], 0, 0, 0);
      acc2[ot] = __builtin_amdgcn_mfma_f32_16x16x32_f16(ah, bl, acc2[ot], 0, 0, 0);
      acc2[ot] = __builtin_amdgcn_mfma_f32_16x16x32_f16(al, bh, acc2[ot], 0, 0, 0);
      acc2[ot] = __builtin_amdgcn_mfma_f32_16x16x32_f16(am, bm, acc2[ot], 0, 0, 0);
    }
  }

  // ---- combine accumulators, write T[n][o]
  const float S1 = 4.8828125e-04f;           // 2^-11
  const float S2 = 2.38418579101562e-07f;    // 2^-22
  #pragma unroll
  for (int ot = 0; ot < 4; ot++)
    #pragma unroll
    for (int r = 0; r < 4; r++)
      T[nbl + ml][ot*16 + quad*4 + r] =
          acc0[ot][r] + S1 * acc1[ot][r] + S2 * acc2[ot][r];
  __syncthreads();

  // ---- final: per thread 16 contiguous o of one n; add bias, split, store
  const int n_l = t >> 2;
  const int oc  = (t & 3) * 16;
  float xv[16];
  #pragma unroll
  for (int j = 0; j < 4; j++) {
    const float4 bj = *(const float4*)&bias[o0 + oc + j*4];
    xv[j*4+0] = T[n_l][oc + j*4+0] + bj.x;
    xv[j*4+1] = T[n_l][oc + j*4+1] + bj.y;
    xv[j*4+2] = T[n_l][oc + j*4+2] + bj.z;
    xv[j*4+3] = T[n_l][oc + j*4+3] + bj.w;
  }
  unsigned short hi[16], lo[16];
  #pragma unroll
  for (int j = 0; j < 16; j++) split_f16(xv[j], hi[j], lo[j]);
  const size_t gb = ((size_t)b * NUM + n0 + n_l) * CDIM + o0 + oc;
  *(u16x8*)&ohi[gb]   = *(u16x8*)&hi[0];
  *(u16x8*)&ohi[gb+8] = *(u16x8*)&hi[8];
  *(u16x8*)&olo[gb]   = *(u16x8*)&lo[0];
  *(u16x8*)&olo[gb+8] = *(u16x8*)&lo[8];
}

// ---------------- score via MFMA (fp16 2-way split, 3 products hh+hl+lh).
// Double-buffered LDS, ONE __syncthreads per head, prefetch after barrier,
// no H0 read (mask lives in topk). LDS 73.7KB -> 2 blocks/CU.
__global__ __launch_bounds__(512, 2) void score_kernel(
    const unsigned short* __restrict__ Qhi, const unsigned short* __restrict__ Qlo,
    const unsigned short* __restrict__ Khi, const unsigned short* __restrict__ Klo,
    float* __restrict__ score)
{
  const int b = blockIdx.z;
  const int i0 = blockIdx.x * 128;
  const int o0 = blockIdx.y * 128;
  const int t = threadIdx.x, lane = t & 63, wave = t >> 6;
  const int m = lane & 15, quad = lane >> 4;
  const int obl = (wave & 1) * 64;
  const int ibl = (wave >> 1) * 32;

  __shared__ unsigned short qsh[2][2][128][36];  // [buf][comp][row][col]
  __shared__ unsigned short ksh[2][2][128][36];

  const int srow = t >> 2;
  const int schk = (t & 3) * 8;
  const size_t gq = ((size_t)b * NUM + o0 + srow) * CDIM + schk;
  const size_t gk = ((size_t)b * NUM + i0 + srow) * CDIM + schk;

  f32x4 ssum[4][2];
  #pragma unroll
  for (int a = 0; a < 4; a++)
    #pragma unroll
    for (int c = 0; c < 2; c++) ssum[a][c] = (f32x4){0.f, 0.f, 0.f, 0.f};

  const float SC = -1.4426950408889634f * 0.17677669529663687f;  // -log2(e)/sqrt(32)

  u16x8 pq[2], pk[2];
  // prologue: head 0 -> buf 0
  pq[0] = *(const u16x8*)&Qhi[gq];
  pq[1] = *(const u16x8*)&Qlo[gq];
  pk[0] = *(const u16x8*)&Khi[gk];
  pk[1] = *(const u16x8*)&Klo[gk];
  *(u16x8*)&qsh[0][0][srow][schk] = pq[0];
  *(u16x8*)&qsh[0][1][srow][schk] = pq[1];
  *(u16x8*)&ksh[0][0][srow][schk] = pk[0];
  *(u16x8*)&ksh[0][1][srow][schk] = pk[1];
  __syncthreads();
  // prefetch head 1 (hidden under compute of head 0)
  pq[0] = *(const u16x8*)&Qhi[gq + 32];
  pq[1] = *(const u16x8*)&Qlo[gq + 32];
  pk[0] = *(const u16x8*)&Khi[gk + 32];
  pk[1] = *(const u16x8*)&Klo[gk + 32];

  for (int h = 0; h < 8; h++) {
    const int c = h & 1;
    f16x8 a[4][2];
    #pragma unroll
    for (int ot = 0; ot < 4; ot++)
      #pragma unroll
      for (int cp = 0; cp < 2; cp++)
        a[ot][cp] = *(const f16x8*)&qsh[c][cp][obl + ot*16 + m][quad*8];
    #pragma unroll
    for (int it = 0; it < 2; it++) {
      const f16x8 b0 = *(const f16x8*)&ksh[c][0][ibl + it*16 + m][quad*8];
      const f16x8 b1 = *(const f16x8*)&ksh[c][1][ibl + it*16 + m][quad*8];
      #pragma unroll
      for (int ot = 0; ot < 4; ot++) {
        f32x4 cc = (f32x4){0.f, 0.f, 0.f, 0.f};
        cc = __builtin_amdgcn_mfma_f32_16x16x32_f16(a[ot][0], b0, cc, 0, 0, 0); // hh
        cc = __builtin_amdgcn_mfma_f32_16x16x32_f16(a[ot][0], b1, cc, 0, 0, 0); // hl
        cc = __builtin_amdgcn_mfma_f32_16x16x32_f16(a[ot][1], b0, cc, 0, 0, 0); // lh
        #pragma unroll
        for (int r = 0; r < 4; r++)
          ssum[ot][it][r] += __builtin_amdgcn_rcpf(1.0f + __builtin_amdgcn_exp2f(cc[r] * SC));
      }
    }
    if (h < 7) {
      // stage head h+1 into the other buffer, one barrier, then prefetch h+2
      *(u16x8*)&qsh[c^1][0][srow][schk] = pq[0];
      *(u16x8*)&qsh[c^1][1][srow][schk] = pq[1];
      *(u16x8*)&ksh[c^1][0][srow][schk] = pk[0];
      *(u16x8*)&ksh[c^1][1][srow][schk] = pk[1];
      __syncthreads();
      if (h < 6) {
        const size_t co = (size_t)(h + 2) * 32;
        pq[0] = *(const u16x8*)&Qhi[gq + co];
        pq[1] = *(const u16x8*)&Qlo[gq + co];
        pk[0] = *(const u16x8*)&Khi[gk + co];
        pk[1] = *(const u16x8*)&Klo[gk + co];
      }
    }
  }

  const int ob = o0 + obl, ib = i0 + ibl;
  #pragma unroll
  for (int ot = 0; ot < 4; ot++)
    #pragma unroll
    for (int it = 0; it < 2; it++)
      #pragma unroll
      for (int r = 0; r < 4; r++) {
        const int row = ob + ot*16 + quad*4 + r;
        const int col = ib + it*16 + m;
        const size_t idx = ((size_t)b * NUM + row) * NUM + col;
        score[idx] = ssum[ot][it][r] * 0.125f;
      }
}

// ---------------- barrier-free fused topk+apply: ONE WAVE PER ROW.
// Applies the H0 mask (moved out of score_kernel): v = H0 ? score : 0.
__global__ __launch_bounds__(256) void topk_apply_kernel(
    float* __restrict__ scoreW, const float* __restrict__ H0,
    float* __restrict__ Hout, const int* __restrict__ iterp,
    float* __restrict__ DvOut)
{
  const int wave = threadIdx.x >> 6, lane = threadIdx.x & 63;
  const int row = blockIdx.x * 4 + wave;
  __shared__ unsigned int hist_all[4][256];
  unsigned int* __restrict__ h = hist_all[wave];
  unsigned int* __restrict__ srow = (unsigned int*)scoreW + (size_t)row * NUM;
  const float* __restrict__ h0row = H0 + (size_t)row * NUM;
  float* __restrict__ Hrow = Hout + (size_t)row * NUM;

  uint4 v[8];
  #pragma unroll
  for (int q = 0; q < 8; q++) {
    const uint4 s4 = ((const uint4*)srow)[lane + 64*q];
    const float4 m4 = ((const float4*)h0row)[lane + 64*q];
    v[q].x = (m4.x != 0.0f) ? s4.x : 0u;
    v[q].y = (m4.y != 0.0f) ? s4.y : 0u;
    v[q].z = (m4.z != 0.0f) ? s4.z : 0u;
    v[q].w = (m4.w != 0.0f) ? s4.w : 0u;
  }

  const int it = iterp[0];
  int k = (int)((double)NUM * 0.1 * (double)(NUM_LAYER - 1 - it) + 0.5);
  if (k < 1) k = 1;
  if (k > NUM) k = NUM;

  unsigned int prefix = 0;
  unsigned int rem = (unsigned int)k;

  for (int pass = 3; pass >= 0; pass--) {
    const int shift = pass * 8;
    const unsigned int pmask = (pass == 3) ? 0u : (0xFFFFFFFFu << (shift + 8));
    *(uint4*)&h[lane*4] = make_uint4(0u, 0u, 0u, 0u);
    __threadfence_block();
    unsigned int zc = 0;
    #pragma unroll
    for (int q = 0; q < 8; q++) {
      const unsigned int vv[4] = {v[q].x, v[q].y, v[q].z, v[q].w};
      #pragma unroll
      for (int e = 0; e < 4; e++) {
        unsigned int val = vv[e];
        if ((val & pmask) == prefix) {
          unsigned int bin = (val >> shift) & 255u;
          if (bin) atomicAdd(&h[bin], 1u);
          else zc++;
        }
      }
    }
    #pragma unroll
    for (int off = 32; off > 0; off >>= 1) zc += __shfl_down(zc, off, 64);
    if (lane == 0) h[0] = zc;
    __threadfence_block();
    // 256-bin suffix scan: lane owns bins [lane*4, lane*4+3]
    const uint4 T = *(const uint4*)&h[lane*4];
    unsigned int s3 = T.w;
    unsigned int s2 = T.z + s3;
    unsigned int s1 = T.y + s2;
    unsigned int s0 = T.x + s1;
    unsigned int tot = s0;
    #pragma unroll
    for (int off = 1; off < 64; off <<= 1) {
      unsigned int y = __shfl_down(tot, off, 64);
      if (lane + off < 64) tot += y;
    }
    const unsigned int ac = tot - s0;    // sum over lanes > lane
    const unsigned int cum[4]   = {s0 + ac, s1 + ac, s2 + ac, s3 + ac};
    const unsigned int above[4] = {s1 + ac, s2 + ac, s3 + ac, ac};
    int fq = -1;
    #pragma unroll
    for (int q = 0; q < 4; q++)
      if (cum[q] >= rem && above[q] < rem) fq = q;
    const unsigned long long mask = __ballot(fq >= 0);
    const int src = (int)(__ffsll((long long)mask) - 1);
    const unsigned int selbin = (fq >= 0) ? (unsigned int)(lane*4 + fq) : 0u;
    const unsigned int nrem   = (fq >= 0) ? (rem - above[fq]) : 0u;
    const unsigned int sel = (unsigned int)__shfl((int)selbin, src, 64);
    rem = (unsigned int)__shfl((int)nrem, src, 64);
    prefix |= (sel << shift);
  }

  const unsigned int amin = prefix;
  float cnt = 0.0f;
  #pragma unroll
  for (int q = 0; q < 8; q++) {
    unsigned int w0 = (v[q].x >= amin) ? v[q].x : 0u;
    unsigned int w1 = (v[q].y >= amin) ? v[q].y : 0u;
    unsigned int w2 = (v[q].z >= amin) ? v[q].z : 0u;
    unsigned int w3 = (v[q].w >= amin) ? v[q].w : 0u;
    float h0 = (w0 != 0u) ? 1.0f : 0.0f;
    float h1 = (w1 != 0u) ? 1.0f : 0.0f;
    float h2 = (w2 != 0u) ? 1.0f : 0.0f;
    float h3 = (w3 != 0u) ? 1.0f : 0.0f;
    cnt += h0 + h1 + h2 + h3;
    ((uint4*)srow)[lane + 64*q] = make_uint4(w0, w1, w2, w3);
    ((float4*)Hrow)[lane + 64*q] = make_float4(h0, h1, h2, h3);
  }
  #pragma unroll
  for (int off = 32; off > 0; off >>= 1) cnt += __shfl_down(cnt, off, 64);
  if (lane == 0) DvOut[row] = 1.0f / (cnt + 1e-10f);
}

// ---------------- column partial sums over o; colH derived from W>0.
__global__ __launch_bounds__(256) void colsum_kernel(
    const float* __restrict__ Wmat,
    float* __restrict__ colH, float* __restrict__ colW)
{
  const int b = blockIdx.z;
  const int i = blockIdx.x * 256 + threadIdx.x;
  const int o0 = blockIdx.y * 64;
  float sh = 0.0f, sw = 0.0f;
  for (int o = 0; o < 64; o++) {
    size_t idx = ((size_t)b * NUM + o0 + o) * NUM + i;
    float w = Wmat[idx];
    sw += w;
    sh += (w > 0.0f) ? 1.0f : 0.0f;
  }
  atomicAdd(&colH[b * NUM + i], sh);
  atomicAdd(&colW[b * NUM + i], sw);
}

// ---------------- De = 1/(colH+eps); W_edge = colW / max(||colW||_2, 1e-12)
__global__ __launch_bounds__(1024) void finalize_kernel(
    const float* __restrict__ colH, const float* __restrict__ colW,
    float* __restrict__ De, float* __restrict__ We)
{
  const int b = blockIdx.x;
  const int t = threadIdx.x;
  float cw[2];
  float sq = 0.0f;
  #pragma unroll
  for (int j = 0; j < 2; j++) {
    int i = t + 1024*j;
    float ch = colH[b * NUM + i];
    De[b * NUM + i] = 1.0f / (ch + 1e-10f);
    cw[j] = colW[b * NUM + i];
    sq += cw[j] * cw[j];
  }
  for (int off = 32; off > 0; off >>= 1) sq += __shfl_down(sq, off, 64);
  __shared__ float red[16];
  __shared__ float s_nrm;
  if ((t & 63) == 0) red[t >> 6] = sq;
  __syncthreads();
  if (t == 0) {
    float tot = 0.0f;
    for (int i2 = 0; i2 < 16; i2++) tot += red[i2];
    s_nrm = fmaxf(sqrtf(tot), 1e-12f);
  }
  __syncthreads();
  #pragma unroll
  for (int j = 0; j < 2; j++)
    We[b * NUM + t + 1024*j] = cw[j] / s_nrm;
}

extern "C" void kernel_launch(void* const* d_in, const int* in_sizes, int n_in,
                              void* d_out, int out_size, void* d_ws, size_t ws_size,
                              hipStream_t stream) {
  const float* H0 = (const float*)d_in[0];
  const float* vf = (const float*)d_in[1];
  const float* ef = (const float*)d_in[2];
  const float* Wq = (const float*)d_in[3];
  const float* bq = (const float*)d_in[4];
  const float* Wk = (const float*)d_in[5];
  const float* bk = (const float*)d_in[6];
  const int* iter = (const int*)d_in[7];

  float* out = (float*)d_out;
  const size_t nH = (size_t)2 * NUM * NUM;
  float* Hout  = out;                 // (2,2048,2048)
  float* Wout  = out + nH;            // (2,2048,2048) — holds score temporarily
  float* DeOut = out + 2 * nH;        // (2,2048,1)
  float* DvOut = DeOut + 2 * NUM;     // (2,2048,1)
  float* WeOut = DvOut + 2 * NUM;     // (2,2048,1)

  float* colH = (float*)d_ws;         // 4096 floats
  float* colW = colH + 2 * NUM;       // 4096 floats

  // fp16 Q/K components (4 x 2MB = 8 MB) live in the H region until topk_apply
  const size_t nC = (size_t)2 * NUM * CDIM;
  unsigned short* base = (unsigned short*)Hout;
  unsigned short* Qhi = base;
  unsigned short* Qlo = base + nC;
  unsigned short* Khi = base + 2 * nC;
  unsigned short* Klo = base + 3 * nC;

  hipMemsetAsync(d_ws, 0, (size_t)2 * 2 * NUM * sizeof(float), stream);

  proj_kernel<<<dim3(NUM/64, CDIM/64, 4), 256, 0, stream>>>(
      Wq, bq, Wk, bk, vf, ef, Qhi, Qlo, Khi, Klo);
  score_kernel<<<dim3(NUM/128, NUM/128, 2), 512, 0, stream>>>(
      Qhi, Qlo, Khi, Klo, Wout);
  topk_apply_kernel<<<dim3(NUM/2), 256, 0, stream>>>(Wout, H0, Hout, iter, DvOut);
  colsum_kernel<<<dim3(NUM/256, NUM/64, 2), 256, 0, stream>>>(Wout, colH, colW);
  finalize_kernel<<<dim3(2), 1024, 0, stream>>>(colH, colW, DeOut, WeOut);
}

// Round 6
// 179.229 us; speedup vs baseline: 1.7715x; 1.0098x over previous
//
#include <hip/hip_runtime.h>
#include <math.h>

#define NUM 2048
#define CDIM 256
#define NUM_LAYER 4

typedef _Float16 f16x8 __attribute__((ext_vector_type(8)));
typedef unsigned short u16x8 __attribute__((ext_vector_type(8)));
typedef float f32x4 __attribute__((ext_vector_type(4)));

// 2-way fp16 split: x = hi + lo + eps, |eps| <= |x| * 2^-23 (11+11 mantissa bits).
static __device__ __forceinline__ void split_f16(float x, unsigned short& h,
                                                 unsigned short& l) {
  _Float16 hi = (_Float16)x;           // RNE
  float r = x - (float)hi;             // exact
  _Float16 lo = (_Float16)r;
  h = __builtin_bit_cast(unsigned short, hi);
  l = __builtin_bit_cast(unsigned short, lo);
}

// Scaled 3-way f16 split: x ~= h + m*2^-11 + l*2^-22, error <= |x|*2^-33
// (below fp32 eps). m,l are residuals PRE-SCALED by 2^11/2^22 so they stay
// f16-normal (no denormal-flush hazard in MFMA); hi is zeroed below f16
// min-normal so tiny x routes into the m component at full precision.
static __device__ __forceinline__ void split3_f16(float x, unsigned short& h,
                                                  unsigned short& m,
                                                  unsigned short& l) {
  float xh = (fabsf(x) >= 6.103515625e-05f) ? x : 0.0f;
  _Float16 hi = (_Float16)xh;
  float r1 = x - (float)hi;            // exact (Dekker split)
  float r1s = r1 * 2048.0f;            // exact pow2 scale
  _Float16 mi = (_Float16)r1s;
  float r2s = (r1s - (float)mi) * 2048.0f;  // exact
  _Float16 lo = (_Float16)r2s;
  h = __builtin_bit_cast(unsigned short, hi);
  m = __builtin_bit_cast(unsigned short, mi);
  l = __builtin_bit_cast(unsigned short, lo);
}

// ---------------- projection via MFMA, fp32-exact-class numerics.
// Scaled 3-way split, three accumulators (hh | hm+mh | hl+lh+mm) combined
// as acc0 + acc1*2^-11 + acc2*2^-22; dropped terms ~2^-33 relative.
// R6: Q is PRE-SCALED by SC = -log2(e)/sqrt(32) before the output split, so
// score_kernel's sigmoid is rcp(1+exp2(cc)) with no per-element multiply.
__global__ __launch_bounds__(256) void proj_kernel(
    const float* __restrict__ Wq, const float* __restrict__ bq,
    const float* __restrict__ Wk, const float* __restrict__ bk,
    const float* __restrict__ vf, const float* __restrict__ ef,
    unsigned short* __restrict__ Qhi, unsigned short* __restrict__ Qlo,
    unsigned short* __restrict__ Khi, unsigned short* __restrict__ Klo)
{
  const int z = blockIdx.z;
  const int b = z >> 1, mm2 = z & 1;
  const float* __restrict__ Wmat = mm2 ? Wk : Wq;
  const float* __restrict__ bias = mm2 ? bk : bq;
  const float* __restrict__ x = (mm2 ? ef : vf) + (size_t)b * CDIM * NUM;
  unsigned short* __restrict__ ohi = mm2 ? Khi : Qhi;
  unsigned short* __restrict__ olo = mm2 ? Klo : Qlo;

  const int n0 = blockIdx.x * 64;
  const int o0 = blockIdx.y * 64;

  __shared__ unsigned short xsh[3][64][36];  // [comp][n][c], pitch 36
  __shared__ unsigned short wsh[3][64][36];  // [comp][o][c]
  __shared__ float T[64][69];                // [n][o] epilogue transpose

  const int t = threadIdx.x, lane = t & 63, wave = t >> 6;
  const int ml = lane & 15, quad = lane >> 4;
  const int nbl = wave * 16;                 // wave's 16-n subtile

  // staging maps
  const int cp = t >> 4;                     // 0..15 -> c pair
  const int nq = t & 15;                     // 0..15 -> n quad
  const int orow = t >> 2;                   // 0..63
  const int cq = (t & 3) * 8;                // 0,8,16,24

  f32x4 acc0[4], acc1[4], acc2[4];
  #pragma unroll
  for (int ot = 0; ot < 4; ot++) {
    acc0[ot] = (f32x4){0.f, 0.f, 0.f, 0.f};
    acc1[ot] = (f32x4){0.f, 0.f, 0.f, 0.f};
    acc2[ot] = (f32x4){0.f, 0.f, 0.f, 0.f};
  }

  for (int cc = 0; cc < CDIM; cc += 32) {
    if (cc) __syncthreads();
    // ---- stage x: 32c x 64n, transpose to [n][c] with 3-way split
    {
      const float4 f4a = *(const float4*)&x[(size_t)(cc + 2*cp) * NUM + n0 + nq*4];
      const float4 f4b = *(const float4*)&x[(size_t)(cc + 2*cp + 1) * NUM + n0 + nq*4];
      const float va[4] = {f4a.x, f4a.y, f4a.z, f4a.w};
      const float vb[4] = {f4b.x, f4b.y, f4b.z, f4b.w};
      #pragma unroll
      for (int j = 0; j < 4; j++) {
        unsigned short h0, m0, l0, h1, m1, l1;
        split3_f16(va[j], h0, m0, l0);
        split3_f16(vb[j], h1, m1, l1);
        *(unsigned*)&xsh[0][nq*4 + j][2*cp] = (unsigned)h0 | ((unsigned)h1 << 16);
        *(unsigned*)&xsh[1][nq*4 + j][2*cp] = (unsigned)m0 | ((unsigned)m1 << 16);
        *(unsigned*)&xsh[2][nq*4 + j][2*cp] = (unsigned)l0 | ((unsigned)l1 << 16);
      }
    }
    // ---- stage W: 64o x 32c, already c-contiguous
    {
      const float4 w0 = *(const float4*)&Wmat[(size_t)(o0 + orow) * CDIM + cc + cq];
      const float4 w1 = *(const float4*)&Wmat[(size_t)(o0 + orow) * CDIM + cc + cq + 4];
      const float wv[8] = {w0.x, w0.y, w0.z, w0.w, w1.x, w1.y, w1.z, w1.w};
      #pragma unroll
      for (int j = 0; j < 4; j++) {
        unsigned short h0, m0, l0, h1, m1, l1;
        split3_f16(wv[2*j],   h0, m0, l0);
        split3_f16(wv[2*j+1], h1, m1, l1);
        *(unsigned*)&wsh[0][orow][cq + 2*j] = (unsigned)h0 | ((unsigned)h1 << 16);
        *(unsigned*)&wsh[1][orow][cq + 2*j] = (unsigned)m0 | ((unsigned)m1 << 16);
        *(unsigned*)&wsh[2][orow][cq + 2*j] = (unsigned)l0 | ((unsigned)l1 << 16);
      }
    }
    __syncthreads();
    // ---- MFMA: A = W rows (o), B = x rows (n); D row<-o, col<-n
    const f16x8 bh = *(const f16x8*)&xsh[0][nbl + ml][quad*8];
    const f16x8 bm = *(const f16x8*)&xsh[1][nbl + ml][quad*8];
    const f16x8 bl = *(const f16x8*)&xsh[2][nbl + ml][quad*8];
    #pragma unroll
    for (int ot = 0; ot < 4; ot++) {
      const f16x8 ah = *(const f16x8*)&wsh[0][ot*16 + ml][quad*8];
      const f16x8 am = *(const f16x8*)&wsh[1][ot*16 + ml][quad*8];
      const f16x8 al = *(const f16x8*)&wsh[2][ot*16 + ml][quad*8];
      acc0[ot] = __builtin_amdgcn_mfma_f32_16x16x32_f16(ah, bh, acc0[ot], 0, 0, 0);
      acc1[ot] = __builtin_amdgcn_mfma_f32_16x16x32_f16(ah, bm, acc1[ot], 0, 0, 0);
      acc1[ot] = __builtin_amdgcn_mfma_f32_16x16x32_f16(am, bh, acc1[ot], 0, 0, 0);
      acc2[ot] = __builtin_amdgcn_mfma_f32_16x16x32_f16(ah, bl, acc2[ot], 0, 0, 0);
      acc2[ot] = __builtin_amdgcn_mfma_f32_16x16x32_f16(al, bh, acc2[ot], 0, 0, 0);
      acc2[ot] = __builtin_amdgcn_mfma_f32_16x16x32_f16(am, bm, acc2[ot], 0, 0, 0);
    }
  }

  // ---- combine accumulators, write T[n][o]
  const float S1 = 4.8828125e-04f;           // 2^-11
  const float S2 = 2.38418579101562e-07f;    // 2^-22
  #pragma unroll
  for (int ot = 0; ot < 4; ot++)
    #pragma unroll
    for (int r = 0; r < 4; r++)
      T[nbl + ml][ot*16 + quad*4 + r] =
          acc0[ot][r] + S1 * acc1[ot][r] + S2 * acc2[ot][r];
  __syncthreads();

  // ---- final: per thread 16 contiguous o of one n; add bias, (Q: scale by
  // SC), split, store. SC fold is exact-class: one fp32 mul (2^-24) below
  // the f16-split error already verified in R2/R3/R5.
  const float SC = -1.4426950408889634f * 0.17677669529663687f;  // -log2(e)/sqrt(32)
  const float osc = mm2 ? 1.0f : SC;
  const int n_l = t >> 2;
  const int oc  = (t & 3) * 16;
  float xv[16];
  #pragma unroll
  for (int j = 0; j < 4; j++) {
    const float4 bj = *(const float4*)&bias[o0 + oc + j*4];
    xv[j*4+0] = (T[n_l][oc + j*4+0] + bj.x) * osc;
    xv[j*4+1] = (T[n_l][oc + j*4+1] + bj.y) * osc;
    xv[j*4+2] = (T[n_l][oc + j*4+2] + bj.z) * osc;
    xv[j*4+3] = (T[n_l][oc + j*4+3] + bj.w) * osc;
  }
  unsigned short hi[16], lo[16];
  #pragma unroll
  for (int j = 0; j < 16; j++) split_f16(xv[j], hi[j], lo[j]);
  const size_t gb = ((size_t)b * NUM + n0 + n_l) * CDIM + o0 + oc;
  *(u16x8*)&ohi[gb]   = *(u16x8*)&hi[0];
  *(u16x8*)&ohi[gb+8] = *(u16x8*)&hi[8];
  *(u16x8*)&olo[gb]   = *(u16x8*)&lo[0];
  *(u16x8*)&olo[gb+8] = *(u16x8*)&lo[8];
}

// ---------------- score via MFMA (fp16 2-way split, 3 products hh+hl+lh).
// Double-buffered LDS, ONE __syncthreads per head, prefetch after barrier.
// R6 stall-structure edits: ALL 12 ds_reads hoisted to head start (single
// lgkm chain), sigmoid is rcp(1+exp2(cc)) (SC pre-folded into Q at proj),
// s_setprio(1) around the MFMA+sigmoid cluster (2 independent blocks/CU
// arbitrate -> T5 regime). LDS 73.7KB -> 2 blocks/CU.
__global__ __launch_bounds__(512, 2) void score_kernel(
    const unsigned short* __restrict__ Qhi, const unsigned short* __restrict__ Qlo,
    const unsigned short* __restrict__ Khi, const unsigned short* __restrict__ Klo,
    float* __restrict__ score)
{
  const int b = blockIdx.z;
  const int i0 = blockIdx.x * 128;
  const int o0 = blockIdx.y * 128;
  const int t = threadIdx.x, lane = t & 63, wave = t >> 6;
  const int m = lane & 15, quad = lane >> 4;
  const int obl = (wave & 1) * 64;
  const int ibl = (wave >> 1) * 32;

  __shared__ unsigned short qsh[2][2][128][36];  // [buf][comp][row][col]
  __shared__ unsigned short ksh[2][2][128][36];

  const int srow = t >> 2;
  const int schk = (t & 3) * 8;
  const size_t gq = ((size_t)b * NUM + o0 + srow) * CDIM + schk;
  const size_t gk = ((size_t)b * NUM + i0 + srow) * CDIM + schk;

  f32x4 ssum[4][2];
  #pragma unroll
  for (int a = 0; a < 4; a++)
    #pragma unroll
    for (int c = 0; c < 2; c++) ssum[a][c] = (f32x4){0.f, 0.f, 0.f, 0.f};

  u16x8 pq[2], pk[2];
  // prologue: head 0 -> buf 0
  pq[0] = *(const u16x8*)&Qhi[gq];
  pq[1] = *(const u16x8*)&Qlo[gq];
  pk[0] = *(const u16x8*)&Khi[gk];
  pk[1] = *(const u16x8*)&Klo[gk];
  *(u16x8*)&qsh[0][0][srow][schk] = pq[0];
  *(u16x8*)&qsh[0][1][srow][schk] = pq[1];
  *(u16x8*)&ksh[0][0][srow][schk] = pk[0];
  *(u16x8*)&ksh[0][1][srow][schk] = pk[1];
  __syncthreads();
  // prefetch head 1 (hidden under compute of head 0)
  pq[0] = *(const u16x8*)&Qhi[gq + 32];
  pq[1] = *(const u16x8*)&Qlo[gq + 32];
  pk[0] = *(const u16x8*)&Khi[gk + 32];
  pk[1] = *(const u16x8*)&Klo[gk + 32];

  for (int h = 0; h < 8; h++) {
    const int c = h & 1;
    // hoist ALL fragment reads: one lgkm wait chain per head
    f16x8 a[4][2], bb[2][2];
    #pragma unroll
    for (int ot = 0; ot < 4; ot++)
      #pragma unroll
      for (int cp = 0; cp < 2; cp++)
        a[ot][cp] = *(const f16x8*)&qsh[c][cp][obl + ot*16 + m][quad*8];
    #pragma unroll
    for (int it = 0; it < 2; it++)
      #pragma unroll
      for (int cp = 0; cp < 2; cp++)
        bb[it][cp] = *(const f16x8*)&ksh[c][cp][ibl + it*16 + m][quad*8];

    __builtin_amdgcn_s_setprio(1);
    #pragma unroll
    for (int it = 0; it < 2; it++) {
      #pragma unroll
      for (int ot = 0; ot < 4; ot++) {
        f32x4 cc = (f32x4){0.f, 0.f, 0.f, 0.f};
        cc = __builtin_amdgcn_mfma_f32_16x16x32_f16(a[ot][0], bb[it][0], cc, 0, 0, 0); // hh
        cc = __builtin_amdgcn_mfma_f32_16x16x32_f16(a[ot][0], bb[it][1], cc, 0, 0, 0); // hl
        cc = __builtin_amdgcn_mfma_f32_16x16x32_f16(a[ot][1], bb[it][0], cc, 0, 0, 0); // lh
        #pragma unroll
        for (int r = 0; r < 4; r++)
          ssum[ot][it][r] += __builtin_amdgcn_rcpf(1.0f + __builtin_amdgcn_exp2f(cc[r]));
      }
    }
    __builtin_amdgcn_s_setprio(0);

    if (h < 7) {
      // stage head h+1 into the other buffer, one barrier, then prefetch h+2
      *(u16x8*)&qsh[c^1][0][srow][schk] = pq[0];
      *(u16x8*)&qsh[c^1][1][srow][schk] = pq[1];
      *(u16x8*)&ksh[c^1][0][srow][schk] = pk[0];
      *(u16x8*)&ksh[c^1][1][srow][schk] = pk[1];
      __syncthreads();
      if (h < 6) {
        const size_t co = (size_t)(h + 2) * 32;
        pq[0] = *(const u16x8*)&Qhi[gq + co];
        pq[1] = *(const u16x8*)&Qlo[gq + co];
        pk[0] = *(const u16x8*)&Khi[gk + co];
        pk[1] = *(const u16x8*)&Klo[gk + co];
      }
    }
  }

  const int ob = o0 + obl, ib = i0 + ibl;
  #pragma unroll
  for (int ot = 0; ot < 4; ot++)
    #pragma unroll
    for (int it = 0; it < 2; it++)
      #pragma unroll
      for (int r = 0; r < 4; r++) {
        const int row = ob + ot*16 + quad*4 + r;
        const int col = ib + it*16 + m;
        const size_t idx = ((size_t)b * NUM + row) * NUM + col;
        score[idx] = ssum[ot][it][r] * 0.125f;
      }
}

// ---------------- barrier-free fused topk+apply: ONE WAVE PER ROW.
// Applies the H0 mask (moved out of score_kernel): v = H0 ? score : 0.
__global__ __launch_bounds__(256) void topk_apply_kernel(
    float* __restrict__ scoreW, const float* __restrict__ H0,
    float* __restrict__ Hout, const int* __restrict__ iterp,
    float* __restrict__ DvOut)
{
  const int wave = threadIdx.x >> 6, lane = threadIdx.x & 63;
  const int row = blockIdx.x * 4 + wave;
  __shared__ unsigned int hist_all[4][256];
  unsigned int* __restrict__ h = hist_all[wave];
  unsigned int* __restrict__ srow = (unsigned int*)scoreW + (size_t)row * NUM;
  const float* __restrict__ h0row = H0 + (size_t)row * NUM;
  float* __restrict__ Hrow = Hout + (size_t)row * NUM;

  uint4 v[8];
  #pragma unroll
  for (int q = 0; q < 8; q++) {
    const uint4 s4 = ((const uint4*)srow)[lane + 64*q];
    const float4 m4 = ((const float4*)h0row)[lane + 64*q];
    v[q].x = (m4.x != 0.0f) ? s4.x : 0u;
    v[q].y = (m4.y != 0.0f) ? s4.y : 0u;
    v[q].z = (m4.z != 0.0f) ? s4.z : 0u;
    v[q].w = (m4.w != 0.0f) ? s4.w : 0u;
  }

  const int it = iterp[0];
  int k = (int)((double)NUM * 0.1 * (double)(NUM_LAYER - 1 - it) + 0.5);
  if (k < 1) k = 1;
  if (k > NUM) k = NUM;

  unsigned int prefix = 0;
  unsigned int rem = (unsigned int)k;

  for (int pass = 3; pass >= 0; pass--) {
    const int shift = pass * 8;
    const unsigned int pmask = (pass == 3) ? 0u : (0xFFFFFFFFu << (shift + 8));
    *(uint4*)&h[lane*4] = make_uint4(0u, 0u, 0u, 0u);
    __threadfence_block();
    unsigned int zc = 0;
    #pragma unroll
    for (int q = 0; q < 8; q++) {
      const unsigned int vv[4] = {v[q].x, v[q].y, v[q].z, v[q].w};
      #pragma unroll
      for (int e = 0; e < 4; e++) {
        unsigned int val = vv[e];
        if ((val & pmask) == prefix) {
          unsigned int bin = (val >> shift) & 255u;
          if (bin) atomicAdd(&h[bin], 1u);
          else zc++;
        }
      }
    }
    #pragma unroll
    for (int off = 32; off > 0; off >>= 1) zc += __shfl_down(zc, off, 64);
    if (lane == 0) h[0] = zc;
    __threadfence_block();
    // 256-bin suffix scan: lane owns bins [lane*4, lane*4+3]
    const uint4 T = *(const uint4*)&h[lane*4];
    unsigned int s3 = T.w;
    unsigned int s2 = T.z + s3;
    unsigned int s1 = T.y + s2;
    unsigned int s0 = T.x + s1;
    unsigned int tot = s0;
    #pragma unroll
    for (int off = 1; off < 64; off <<= 1) {
      unsigned int y = __shfl_down(tot, off, 64);
      if (lane + off < 64) tot += y;
    }
    const unsigned int ac = tot - s0;    // sum over lanes > lane
    const unsigned int cum[4]   = {s0 + ac, s1 + ac, s2 + ac, s3 + ac};
    const unsigned int above[4] = {s1 + ac, s2 + ac, s3 + ac, ac};
    int fq = -1;
    #pragma unroll
    for (int q = 0; q < 4; q++)
      if (cum[q] >= rem && above[q] < rem) fq = q;
    const unsigned long long mask = __ballot(fq >= 0);
    const int src = (int)(__ffsll((long long)mask) - 1);
    const unsigned int selbin = (fq >= 0) ? (unsigned int)(lane*4 + fq) : 0u;
    const unsigned int nrem   = (fq >= 0) ? (rem - above[fq]) : 0u;
    const unsigned int sel = (unsigned int)__shfl((int)selbin, src, 64);
    rem = (unsigned int)__shfl((int)nrem, src, 64);
    prefix |= (sel << shift);
  }

  const unsigned int amin = prefix;
  float cnt = 0.0f;
  #pragma unroll
  for (int q = 0; q < 8; q++) {
    unsigned int w0 = (v[q].x >= amin) ? v[q].x : 0u;
    unsigned int w1 = (v[q].y >= amin) ? v[q].y : 0u;
    unsigned int w2 = (v[q].z >= amin) ? v[q].z : 0u;
    unsigned int w3 = (v[q].w >= amin) ? v[q].w : 0u;
    float h0 = (w0 != 0u) ? 1.0f : 0.0f;
    float h1 = (w1 != 0u) ? 1.0f : 0.0f;
    float h2 = (w2 != 0u) ? 1.0f : 0.0f;
    float h3 = (w3 != 0u) ? 1.0f : 0.0f;
    cnt += h0 + h1 + h2 + h3;
    ((uint4*)srow)[lane + 64*q] = make_uint4(w0, w1, w2, w3);
    ((float4*)Hrow)[lane + 64*q] = make_float4(h0, h1, h2, h3);
  }
  #pragma unroll
  for (int off = 32; off > 0; off >>= 1) cnt += __shfl_down(cnt, off, 64);
  if (lane == 0) DvOut[row] = 1.0f / (cnt + 1e-10f);
}

// ---------------- column partial sums over o; colH derived from W>0.
__global__ __launch_bounds__(256) void colsum_kernel(
    const float* __restrict__ Wmat,
    float* __restrict__ colH, float* __restrict__ colW)
{
  const int b = blockIdx.z;
  const int i = blockIdx.x * 256 + threadIdx.x;
  const int o0 = blockIdx.y * 64;
  float sh = 0.0f, sw = 0.0f;
  for (int o = 0; o < 64; o++) {
    size_t idx = ((size_t)b * NUM + o0 + o) * NUM + i;
    float w = Wmat[idx];
    sw += w;
    sh += (w > 0.0f) ? 1.0f : 0.0f;
  }
  atomicAdd(&colH[b * NUM + i], sh);
  atomicAdd(&colW[b * NUM + i], sw);
}

// ---------------- De = 1/(colH+eps); W_edge = colW / max(||colW||_2, 1e-12)
__global__ __launch_bounds__(1024) void finalize_kernel(
    const float* __restrict__ colH, const float* __restrict__ colW,
    float* __restrict__ De, float* __restrict__ We)
{
  const int b = blockIdx.x;
  const int t = threadIdx.x;
  float cw[2];
  float sq = 0.0f;
  #pragma unroll
  for (int j = 0; j < 2; j++) {
    int i = t + 1024*j;
    float ch = colH[b * NUM + i];
    De[b * NUM + i] = 1.0f / (ch + 1e-10f);
    cw[j] = colW[b * NUM + i];
    sq += cw[j] * cw[j];
  }
  for (int off = 32; off > 0; off >>= 1) sq += __shfl_down(sq, off, 64);
  __shared__ float red[16];
  __shared__ float s_nrm;
  if ((t & 63) == 0) red[t >> 6] = sq;
  __syncthreads();
  if (t == 0) {
    float tot = 0.0f;
    for (int i2 = 0; i2 < 16; i2++) tot += red[i2];
    s_nrm = fmaxf(sqrtf(tot), 1e-12f);
  }
  __syncthreads();
  #pragma unroll
  for (int j = 0; j < 2; j++)
    We[b * NUM + t + 1024*j] = cw[j] / s_nrm;
}

extern "C" void kernel_launch(void* const* d_in, const int* in_sizes, int n_in,
                              void* d_out, int out_size, void* d_ws, size_t ws_size,
                              hipStream_t stream) {
  const float* H0 = (const float*)d_in[0];
  const float* vf = (const float*)d_in[1];
  const float* ef = (const float*)d_in[2];
  const float* Wq = (const float*)d_in[3];
  const float* bq = (const float*)d_in[4];
  const float* Wk = (const float*)d_in[5];
  const float* bk = (const float*)d_in[6];
  const int* iter = (const int*)d_in[7];

  float* out = (float*)d_out;
  const size_t nH = (size_t)2 * NUM * NUM;
  float* Hout  = out;                 // (2,2048,2048)
  float* Wout  = out + nH;            // (2,2048,2048) — holds score temporarily
  float* DeOut = out + 2 * nH;        // (2,2048,1)
  float* DvOut = DeOut + 2 * NUM;     // (2,2048,1)
  float* WeOut = DvOut + 2 * NUM;     // (2,2048,1)

  float* colH = (float*)d_ws;         // 4096 floats
  float* colW = colH + 2 * NUM;       // 4096 floats

  // fp16 Q/K components (4 x 2MB = 8 MB) live in the H region until topk_apply
  const size_t nC = (size_t)2 * NUM * CDIM;
  unsigned short* base = (unsigned short*)Hout;
  unsigned short* Qhi = base;
  unsigned short* Qlo = base + nC;
  unsigned short* Khi = base + 2 * nC;
  unsigned short* Klo = base + 3 * nC;

  hipMemsetAsync(d_ws, 0, (size_t)2 * 2 * NUM * sizeof(float), stream);

  proj_kernel<<<dim3(NUM/64, CDIM/64, 4), 256, 0, stream>>>(
      Wq, bq, Wk, bk, vf, ef, Qhi, Qlo, Khi, Klo);
  score_kernel<<<dim3(NUM/128, NUM/128, 2), 512, 0, stream>>>(
      Qhi, Qlo, Khi, Klo, Wout);
  topk_apply_kernel<<<dim3(NUM/2), 256, 0, stream>>>(Wout, H0, Hout, iter, DvOut);
  colsum_kernel<<<dim3(NUM/256, NUM/64, 2), 256, 0, stream>>>(Wout, colH, colW);
  finalize_kernel<<<dim3(2), 1024, 0, stream>>>(colH, colW, DeOut, WeOut);
}